// Round 7
// baseline (813.368 us; speedup 1.0000x reference)
//
#include <hip/hip_runtime.h>
#include <stdint.h>

#define NN 100000
#define EE 1600000
#define DD 64
#define NB 391   // ceil(NN/256)

// ---------------- CSR build via linked lists (single atomic per edge) ----------------

__global__ void build_kernel(const int* __restrict__ dst,
                             int* __restrict__ head, int* __restrict__ next) {
    int e = blockIdx.x * blockDim.x + threadIdx.x;
    if (e < EE) {
        next[e] = atomicExch(&head[dst[e]], e);   // only atomic in the build
    }
}

// 1 thread/node: chain length -> cnt (no atomics)
__global__ void count_walk(const int* __restrict__ head, const int* __restrict__ next,
                           int* __restrict__ cnt) {
    int i = blockIdx.x * 256 + threadIdx.x;
    if (i >= NN) return;
    int c = 0;
    for (int p = head[i]; p >= 0; p = next[p]) c++;
    cnt[i] = c;
}

__global__ void scan1(const int* __restrict__ cnt, int* __restrict__ partial) {
    __shared__ int s[256];
    int i = blockIdx.x * 256 + threadIdx.x;
    int v = (i < NN) ? cnt[i] : 0;
    s[threadIdx.x] = v;
    __syncthreads();
    for (int off = 128; off > 0; off >>= 1) {
        if (threadIdx.x < off) s[threadIdx.x] += s[threadIdx.x + off];
        __syncthreads();
    }
    if (threadIdx.x == 0) partial[blockIdx.x] = s[0];
}

__global__ void scan2(int* __restrict__ partial) {
    __shared__ int s[512];
    int t = threadIdx.x;
    int v = (t < NB) ? partial[t] : 0;
    s[t] = v;
    __syncthreads();
    for (int off = 1; off < 512; off <<= 1) {
        int add = (t >= off) ? s[t - off] : 0;
        __syncthreads();
        s[t] += add;
        __syncthreads();
    }
    if (t < NB) partial[t] = s[t] - v;  // exclusive
}

__global__ void scan3(const int* __restrict__ cnt, const int* __restrict__ partial,
                      int* __restrict__ offsets) {
    __shared__ int s[256];
    int t = threadIdx.x;
    int i = blockIdx.x * 256 + t;
    int v = (i < NN) ? cnt[i] : 0;
    s[t] = v;
    __syncthreads();
    for (int off = 1; off < 256; off <<= 1) {
        int add = (t >= off) ? s[t - off] : 0;
        __syncthreads();
        s[t] += add;
        __syncthreads();
    }
    int excl = s[t] - v + partial[blockIdx.x];
    if (i < NN) {
        offsets[i] = excl;
        if (i == NN - 1) offsets[NN] = excl + v;
    }
}

// 1 thread per node: walk linked list, write csr contiguously (full-line writes)
__global__ void walk_kernel(const int* __restrict__ head, const int* __restrict__ next,
                            const int* __restrict__ srcA, const int* __restrict__ offsets,
                            int* __restrict__ csr) {
    int i = blockIdx.x * 256 + threadIdx.x;
    if (i >= NN) return;
    int p = head[i];
    int w = offsets[i];
    while (p >= 0) {
        csr[w++] = srcA[p];
        p = next[p];
    }
}

// ---------------- GEMM, split by matrix: blockIdx.y in {0,1,2} selects Wl/Wr/Ws ----------------
// 256 threads, 32 rows/block, one 64x64 weight matrix in LDS (16.4 KB -> many blocks/CU).
// Wt[k][c] layout: lane reads bank c%32, 2-way aliasing = conflict-free.
// h rows read direct from global with wave-uniform float4 address -> L1 broadcast.

__global__ __launch_bounds__(256) void gemm_part(
    const float* __restrict__ hin,
    const float* __restrict__ Wl, const float* __restrict__ Wr, const float* __restrict__ Ws,
    const float* __restrict__ bl, const float* __restrict__ br, const float* __restrict__ bs,
    float* __restrict__ Xl, float* __restrict__ XRS) {
    int j = blockIdx.y;
    const float* W = (j == 0) ? Wl : ((j == 1) ? Wr : Ws);
    const float* B = (j == 0) ? bl : ((j == 1) ? br : bs);

    __shared__ float Wt[64][64];
    __shared__ float bsh[64];
    int t = threadIdx.x;
    for (int idx = t; idx < 4096; idx += 256) Wt[idx >> 6][idx & 63] = W[idx];
    if (t < 64) bsh[t] = B[t];
    __syncthreads();

    int c  = t & 63;
    int rg = t >> 6;  // 0..3 -> rows rg*8 .. rg*8+7
    int row0 = blockIdx.x * 32 + rg * 8;

    int rowS[8];
#pragma unroll
    for (int rr = 0; rr < 8; rr++) {
        int r = row0 + rr;
        rowS[rr] = (r < NN) ? r : (NN - 1);
    }

    float acc[8];
#pragma unroll
    for (int r = 0; r < 8; r++) acc[r] = 0.f;

#pragma unroll 4
    for (int k0 = 0; k0 < 64; k0 += 4) {
        float w0 = Wt[k0 + 0][c];
        float w1 = Wt[k0 + 1][c];
        float w2 = Wt[k0 + 2][c];
        float w3 = Wt[k0 + 3][c];
#pragma unroll
        for (int rr = 0; rr < 8; rr++) {
            float4 hv = *(const float4*)&hin[(size_t)rowS[rr] * 64 + k0];  // wave-uniform -> broadcast
            acc[rr] += hv.x * w0 + hv.y * w1 + hv.z * w2 + hv.w * w3;
        }
    }

    float b = bsh[c];
    if (j == 0) {
#pragma unroll
        for (int rr = 0; rr < 8; rr++) {
            int row = row0 + rr;
            if (row < NN) Xl[(size_t)row * 64 + c] = acc[rr] + b;
        }
    } else {
        int coff = (j == 1) ? 0 : 64;
#pragma unroll
        for (int rr = 0; rr < 8; rr++) {
            int row = row0 + rr;
            if (row < NN) XRS[(size_t)row * 128 + coff + c] = acc[rr] + b;
        }
    }
}

// ---------------- per-node attention aggregation ----------------
// One wave per dst node; 4 edges in parallel, 16 lanes per edge.
// Lane l owns features 4*(l&15) .. 4*(l&15)+3 of its edge's xl as a float4.

__device__ __forceinline__ float group_sum16(float t) {
    t += __int_as_float(__builtin_amdgcn_update_dpp(0, __float_as_int(t), 0xB1, 0xF, 0xF, true));   // xor1
    t += __int_as_float(__builtin_amdgcn_update_dpp(0, __float_as_int(t), 0x4E, 0xF, 0xF, true));   // xor2
    t += __int_as_float(__builtin_amdgcn_update_dpp(0, __float_as_int(t), 0x141, 0xF, 0xF, true));  // row_half_mirror ~ xor4
    t += __int_as_float(__builtin_amdgcn_update_dpp(0, __float_as_int(t), 0x140, 0xF, 0xF, true));  // row_mirror ~ xor8
    return t;
}

__device__ __forceinline__ float lrelu(float v) {
    return (v > 0.f) ? v : 0.2f * v;
}

__global__ __launch_bounds__(256) void node_kernel(
    const float* __restrict__ Xl, const float* __restrict__ XRS,
    const int* __restrict__ offsets, const int* __restrict__ csr,
    const float* __restrict__ att, const float* __restrict__ bg,
    float* __restrict__ hout, int do_relu,
    const float* __restrict__ Wout, const float* __restrict__ bout,
    float* __restrict__ outp, int do_out) {
    int lane = threadIdx.x & 63;
    int wid  = threadIdx.x >> 6;
    int i = blockIdx.x * 4 + wid;
    if (i >= NN) return;
    int sub = lane & 15;   // feature-quad index: features 4*sub..4*sub+3
    int grp = lane >> 4;   // edge slot 0..3

    float4 xr4  = *(const float4*)&XRS[(size_t)i * 128 + sub * 4];
    float4 att4 = *(const float4*)&att[sub * 4];

    float aggx = 0.f, aggy = 0.f, aggz = 0.f, aggw = 0.f;
    float denom = 0.f;
    int beg = offsets[i], end = offsets[i + 1];

    for (int j0 = beg; j0 < end; j0 += 8) {
        int jA = j0 + grp, jB = j0 + grp + 4;
        bool vA = jA < end, vB = jB < end;
        int sA = csr[vA ? jA : beg];
        int sB = csr[vB ? jB : beg];
        float4 xA = *(const float4*)&Xl[(size_t)sA * 64 + sub * 4];
        float4 xB = *(const float4*)&Xl[(size_t)sB * 64 + sub * 4];

        float tA = lrelu(xA.x + xr4.x) * att4.x + lrelu(xA.y + xr4.y) * att4.y
                 + lrelu(xA.z + xr4.z) * att4.z + lrelu(xA.w + xr4.w) * att4.w;
        float tB = lrelu(xB.x + xr4.x) * att4.x + lrelu(xB.y + xr4.y) * att4.y
                 + lrelu(xB.z + xr4.z) * att4.z + lrelu(xB.w + xr4.w) * att4.w;
        tA = group_sum16(tA);
        tB = group_sum16(tB);
        float aA = vA ? __expf(tA) : 0.f;
        float aB = vB ? __expf(tB) : 0.f;

        aggx += aA * xA.x + aB * xB.x;
        aggy += aA * xA.y + aB * xB.y;
        aggz += aA * xA.z + aB * xB.z;
        aggw += aA * xA.w + aB * xB.w;
        denom += aA + aB;
    }

    // combine the 4 edge groups (once per node)
#pragma unroll
    for (int m = 16; m <= 32; m <<= 1) {
        aggx  += __shfl_xor(aggx, m, 64);
        aggy  += __shfl_xor(aggy, m, 64);
        aggz  += __shfl_xor(aggz, m, 64);
        aggw  += __shfl_xor(aggw, m, 64);
        denom += __shfl_xor(denom, m, 64);
    }

    float inv = (denom > 0.f) ? (1.0f / denom) : 0.f;
    float4 sk4 = *(const float4*)&XRS[(size_t)i * 128 + 64 + sub * 4];
    float4 bg4 = *(const float4*)&bg[sub * 4];
    float4 res;
    res.x = aggx * inv + bg4.x + sk4.x;
    res.y = aggy * inv + bg4.y + sk4.y;
    res.z = aggz * inv + bg4.z + sk4.z;
    res.w = aggw * inv + bg4.w + sk4.w;
    if (do_relu) {
        res.x = fmaxf(res.x, 0.f); res.y = fmaxf(res.y, 0.f);
        res.z = fmaxf(res.z, 0.f); res.w = fmaxf(res.w, 0.f);
    }
    if (do_out) {
        // fused final projection: out[i][j] = sum_f h[f] * Wout[f][j] + bout[j]
        float4 w01 = *(const float4*)&Wout[8 * sub];       // W[4s+0][0..1], W[4s+1][0..1]
        float4 w23 = *(const float4*)&Wout[8 * sub + 4];   // W[4s+2][0..1], W[4s+3][0..1]
        float o0 = res.x * w01.x + res.y * w01.z + res.z * w23.x + res.w * w23.z;
        float o1 = res.x * w01.y + res.y * w01.w + res.z * w23.y + res.w * w23.w;
        o0 = group_sum16(o0);
        o1 = group_sum16(o1);
        if (lane == 0) {
            outp[(size_t)i * 2 + 0] = o0 + bout[0];
            outp[(size_t)i * 2 + 1] = o1 + bout[1];
        }
    } else {
        if (grp == 0) *(float4*)&hout[(size_t)i * 64 + sub * 4] = res;
    }
}

// ---------------- launch ----------------

extern "C" void kernel_launch(void* const* d_in, const int* in_sizes, int n_in,
                              void* d_out, int out_size, void* d_ws, size_t ws_size,
                              hipStream_t stream) {
    const float* x    = (const float*)d_in[0];
    const int*   ei   = (const int*)d_in[1];   // [2][E]: row0=src, row1=dst
    const float* Wl   = (const float*)d_in[2];
    const float* bl   = (const float*)d_in[3];
    const float* Wr   = (const float*)d_in[4];
    const float* br   = (const float*)d_in[5];
    const float* att  = (const float*)d_in[6];
    const float* bg   = (const float*)d_in[7];
    const float* Ws   = (const float*)d_in[8];
    const float* bs   = (const float*)d_in[9];
    const float* Wout = (const float*)d_in[10];
    const float* bout = (const float*)d_in[11];
    float* out = (float*)d_out;

    size_t off = 0;
    char* base = (char*)d_ws;
    auto alloc = [&](size_t bytes) -> void* {
        void* p = base + off;
        off += (bytes + 255) & ~(size_t)255;
        return p;
    };
    float* Xl     = (float*)alloc((size_t)NN * 64 * 4);
    float* XRS    = (float*)alloc((size_t)NN * 128 * 4);
    float* h      = (float*)alloc((size_t)NN * 64 * 4);
    int*   cnt    = (int*)alloc((size_t)NN * 4);
    int*   headA  = (int*)alloc((size_t)NN * 4);
    int*   nextA  = (int*)alloc((size_t)EE * 4);
    int*   offs   = (int*)alloc((size_t)(NN + 1) * 4);
    int*   csr    = (int*)alloc((size_t)EE * 4);
    int*   part   = (int*)alloc(512 * 4);

    const int* src = ei;
    const int* dst = ei + EE;

    hipMemsetAsync(headA, 0xFF, (size_t)NN * 4, stream);   // -1
    build_kernel<<<(EE + 255) / 256, 256, 0, stream>>>(dst, headA, nextA);
    count_walk<<<NB, 256, 0, stream>>>(headA, nextA, cnt);
    scan1<<<NB, 256, 0, stream>>>(cnt, part);
    scan2<<<1, 512, 0, stream>>>(part);
    scan3<<<NB, 256, 0, stream>>>(cnt, part, offs);
    walk_kernel<<<NB, 256, 0, stream>>>(headA, nextA, src, offs, csr);

    dim3 ggrid((NN + 31) / 32, 3);
    const float* hin = x;
    for (int L = 0; L < 3; L++) {
        gemm_part<<<ggrid, 256, 0, stream>>>(
            hin, Wl + L * 4096, Wr + L * 4096, Ws + L * 4096,
            bl + L * 64, br + L * 64, bs + L * 64, Xl, XRS);
        node_kernel<<<NN / 4, 256, 0, stream>>>(
            Xl, XRS, offs, csr, att + L * 64, bg + L * 64, h, (L < 2) ? 1 : 0,
            Wout, bout, out, (L == 2) ? 1 : 0);
        hin = h;
    }
}

// Round 8
// 515.136 us; speedup vs baseline: 1.5789x; 1.5789x over previous
//
#include <hip/hip_runtime.h>
#include <stdint.h>

#define NN 100000
#define EE 1600000
#define DD 64
#define NB 391   // ceil(NN/256)

// ---------------- CSR build via linked lists (single atomic per edge) ----------------

__global__ void build_kernel(const int* __restrict__ dst,
                             int* __restrict__ head, int* __restrict__ next) {
    int e = blockIdx.x * blockDim.x + threadIdx.x;
    if (e < EE) {
        next[e] = atomicExch(&head[dst[e]], e);   // only atomic in the build
    }
}

// 1 thread/node: chain length -> cnt (no atomics)
__global__ void count_walk(const int* __restrict__ head, const int* __restrict__ next,
                           int* __restrict__ cnt) {
    int i = blockIdx.x * 256 + threadIdx.x;
    if (i >= NN) return;
    int c = 0;
    for (int p = head[i]; p >= 0; p = next[p]) c++;
    cnt[i] = c;
}

__global__ void scan1(const int* __restrict__ cnt, int* __restrict__ partial) {
    __shared__ int s[256];
    int i = blockIdx.x * 256 + threadIdx.x;
    int v = (i < NN) ? cnt[i] : 0;
    s[threadIdx.x] = v;
    __syncthreads();
    for (int off = 128; off > 0; off >>= 1) {
        if (threadIdx.x < off) s[threadIdx.x] += s[threadIdx.x + off];
        __syncthreads();
    }
    if (threadIdx.x == 0) partial[blockIdx.x] = s[0];
}

__global__ void scan2(int* __restrict__ partial) {
    __shared__ int s[512];
    int t = threadIdx.x;
    int v = (t < NB) ? partial[t] : 0;
    s[t] = v;
    __syncthreads();
    for (int off = 1; off < 512; off <<= 1) {
        int add = (t >= off) ? s[t - off] : 0;
        __syncthreads();
        s[t] += add;
        __syncthreads();
    }
    if (t < NB) partial[t] = s[t] - v;  // exclusive
}

__global__ void scan3(const int* __restrict__ cnt, const int* __restrict__ partial,
                      int* __restrict__ offsets) {
    __shared__ int s[256];
    int t = threadIdx.x;
    int i = blockIdx.x * 256 + t;
    int v = (i < NN) ? cnt[i] : 0;
    s[t] = v;
    __syncthreads();
    for (int off = 1; off < 256; off <<= 1) {
        int add = (t >= off) ? s[t - off] : 0;
        __syncthreads();
        s[t] += add;
        __syncthreads();
    }
    int excl = s[t] - v + partial[blockIdx.x];
    if (i < NN) {
        offsets[i] = excl;
        if (i == NN - 1) offsets[NN] = excl + v;
    }
}

// 1 thread per node: walk linked list, write csr contiguously (full-line writes)
__global__ void walk_kernel(const int* __restrict__ head, const int* __restrict__ next,
                            const int* __restrict__ srcA, const int* __restrict__ offsets,
                            int* __restrict__ csr) {
    int i = blockIdx.x * 256 + threadIdx.x;
    if (i >= NN) return;
    int p = head[i];
    int w = offsets[i];
    while (p >= 0) {
        csr[w++] = srcA[p];
        p = next[p];
    }
}

// ---------------- fused 3-way GEMM (R5 structure, 512 threads / 64 rows) ----------------
// Xl = h@Wl+bl, XRS = [h@Wr+br | h@Ws+bs]. One block does all 3 matrices (amortizes h).
// LDS: Wlds 49.2KB + ht 16KB = 66KB -> 2 blocks/CU = 16 waves/CU (2x R5's occupancy).
// Weight reads Wlds[k][C]: bank = C%32, 2-way aliasing = free (R5 measured 0 conflicts).
// ht reads are wave-uniform (rg per-wave) -> LDS broadcast, conflict-free.

__global__ __launch_bounds__(512) void gemm_fused(
    const float* __restrict__ hin,
    const float* __restrict__ Wl, const float* __restrict__ Wr, const float* __restrict__ Ws,
    const float* __restrict__ bl, const float* __restrict__ br, const float* __restrict__ bs,
    float* __restrict__ Xl, float* __restrict__ XRS) {
    __shared__ float Wlds[64][192];
    __shared__ float bias[192];
    __shared__ float ht[64][64];
    int t = threadIdx.x;
    for (int idx = t; idx < 4096; idx += 512) {
        int k = idx >> 6, c = idx & 63;
        Wlds[k][c]        = Wl[idx];
        Wlds[k][64 + c]   = Wr[idx];
        Wlds[k][128 + c]  = Ws[idx];
    }
    if (t < 192) bias[t] = (t < 64) ? bl[t] : (t < 128 ? br[t - 64] : bs[t - 128]);

    int row0 = blockIdx.x * 64;
    // stage 64x64 h tile: 1024 float4, 2 per thread, coalesced
    for (int idx = t; idx < 1024; idx += 512) {
        int r = idx >> 4, q = idx & 15;
        int grow = row0 + r;
        float4 v = (grow < NN) ? *(const float4*)&hin[(size_t)grow * 64 + q * 4]
                               : make_float4(0.f, 0.f, 0.f, 0.f);
        *(float4*)&ht[r][q * 4] = v;
    }
    __syncthreads();

    int c  = t & 63;
    int rg = t >> 6;  // 0..7 -> rows rg*8 .. rg*8+7 (wave-uniform)
    float acc0[8], acc1[8], acc2[8];
#pragma unroll
    for (int r = 0; r < 8; r++) { acc0[r] = 0.f; acc1[r] = 0.f; acc2[r] = 0.f; }

#pragma unroll 2
    for (int k0 = 0; k0 < 64; k0 += 4) {
        float w0[4], w1[4], w2[4];
#pragma unroll
        for (int kk = 0; kk < 4; kk++) {
            w0[kk] = Wlds[k0 + kk][c];
            w1[kk] = Wlds[k0 + kk][64 + c];
            w2[kk] = Wlds[k0 + kk][128 + c];
        }
#pragma unroll
        for (int rr = 0; rr < 8; rr++) {
            float4 hv = *(const float4*)&ht[rg * 8 + rr][k0];  // wave-uniform -> broadcast
            acc0[rr] += hv.x * w0[0] + hv.y * w0[1] + hv.z * w0[2] + hv.w * w0[3];
            acc1[rr] += hv.x * w1[0] + hv.y * w1[1] + hv.z * w1[2] + hv.w * w1[3];
            acc2[rr] += hv.x * w2[0] + hv.y * w2[1] + hv.z * w2[2] + hv.w * w2[3];
        }
    }
    float b0 = bias[c], b1 = bias[64 + c], b2 = bias[128 + c];
#pragma unroll
    for (int rr = 0; rr < 8; rr++) {
        int row = row0 + rg * 8 + rr;
        if (row < NN) {
            Xl[(size_t)row * 64 + c]        = acc0[rr] + b0;
            XRS[(size_t)row * 128 + c]      = acc1[rr] + b1;
            XRS[(size_t)row * 128 + 64 + c] = acc2[rr] + b2;
        }
    }
}

// ---------------- per-node attention aggregation ----------------
// One wave per dst node; 4 edges in parallel, 16 lanes per edge.
// Lane l owns features 4*(l&15) .. 4*(l&15)+3 of its edge's xl as a float4.

__device__ __forceinline__ float group_sum16(float t) {
    t += __int_as_float(__builtin_amdgcn_update_dpp(0, __float_as_int(t), 0xB1, 0xF, 0xF, true));   // xor1
    t += __int_as_float(__builtin_amdgcn_update_dpp(0, __float_as_int(t), 0x4E, 0xF, 0xF, true));   // xor2
    t += __int_as_float(__builtin_amdgcn_update_dpp(0, __float_as_int(t), 0x141, 0xF, 0xF, true));  // row_half_mirror ~ xor4
    t += __int_as_float(__builtin_amdgcn_update_dpp(0, __float_as_int(t), 0x140, 0xF, 0xF, true));  // row_mirror ~ xor8
    return t;
}

__device__ __forceinline__ float lrelu(float v) {
    return (v > 0.f) ? v : 0.2f * v;
}

__global__ __launch_bounds__(256) void node_kernel(
    const float* __restrict__ Xl, const float* __restrict__ XRS,
    const int* __restrict__ offsets, const int* __restrict__ csr,
    const float* __restrict__ att, const float* __restrict__ bg,
    float* __restrict__ hout, int do_relu,
    const float* __restrict__ Wout, const float* __restrict__ bout,
    float* __restrict__ outp, int do_out) {
    int lane = threadIdx.x & 63;
    int wid  = threadIdx.x >> 6;
    int i = blockIdx.x * 4 + wid;
    if (i >= NN) return;
    int sub = lane & 15;   // feature-quad index: features 4*sub..4*sub+3
    int grp = lane >> 4;   // edge slot 0..3

    float4 xr4  = *(const float4*)&XRS[(size_t)i * 128 + sub * 4];
    float4 att4 = *(const float4*)&att[sub * 4];

    float aggx = 0.f, aggy = 0.f, aggz = 0.f, aggw = 0.f;
    float denom = 0.f;
    int beg = offsets[i], end = offsets[i + 1];

    for (int j0 = beg; j0 < end; j0 += 8) {
        int jA = j0 + grp, jB = j0 + grp + 4;
        bool vA = jA < end, vB = jB < end;
        int sA = csr[vA ? jA : beg];
        int sB = csr[vB ? jB : beg];
        float4 xA = *(const float4*)&Xl[(size_t)sA * 64 + sub * 4];
        float4 xB = *(const float4*)&Xl[(size_t)sB * 64 + sub * 4];

        float tA = lrelu(xA.x + xr4.x) * att4.x + lrelu(xA.y + xr4.y) * att4.y
                 + lrelu(xA.z + xr4.z) * att4.z + lrelu(xA.w + xr4.w) * att4.w;
        float tB = lrelu(xB.x + xr4.x) * att4.x + lrelu(xB.y + xr4.y) * att4.y
                 + lrelu(xB.z + xr4.z) * att4.z + lrelu(xB.w + xr4.w) * att4.w;
        tA = group_sum16(tA);
        tB = group_sum16(tB);
        float aA = vA ? __expf(tA) : 0.f;
        float aB = vB ? __expf(tB) : 0.f;

        aggx += aA * xA.x + aB * xB.x;
        aggy += aA * xA.y + aB * xB.y;
        aggz += aA * xA.z + aB * xB.z;
        aggw += aA * xA.w + aB * xB.w;
        denom += aA + aB;
    }

    // combine the 4 edge groups (once per node)
#pragma unroll
    for (int m = 16; m <= 32; m <<= 1) {
        aggx  += __shfl_xor(aggx, m, 64);
        aggy  += __shfl_xor(aggy, m, 64);
        aggz  += __shfl_xor(aggz, m, 64);
        aggw  += __shfl_xor(aggw, m, 64);
        denom += __shfl_xor(denom, m, 64);
    }

    float inv = (denom > 0.f) ? (1.0f / denom) : 0.f;
    float4 sk4 = *(const float4*)&XRS[(size_t)i * 128 + 64 + sub * 4];
    float4 bg4 = *(const float4*)&bg[sub * 4];
    float4 res;
    res.x = aggx * inv + bg4.x + sk4.x;
    res.y = aggy * inv + bg4.y + sk4.y;
    res.z = aggz * inv + bg4.z + sk4.z;
    res.w = aggw * inv + bg4.w + sk4.w;
    if (do_relu) {
        res.x = fmaxf(res.x, 0.f); res.y = fmaxf(res.y, 0.f);
        res.z = fmaxf(res.z, 0.f); res.w = fmaxf(res.w, 0.f);
    }
    if (do_out) {
        // fused final projection: out[i][j] = sum_f h[f] * Wout[f][j] + bout[j]
        float4 w01 = *(const float4*)&Wout[8 * sub];       // W[4s+0][0..1], W[4s+1][0..1]
        float4 w23 = *(const float4*)&Wout[8 * sub + 4];   // W[4s+2][0..1], W[4s+3][0..1]
        float o0 = res.x * w01.x + res.y * w01.z + res.z * w23.x + res.w * w23.z;
        float o1 = res.x * w01.y + res.y * w01.w + res.z * w23.y + res.w * w23.w;
        o0 = group_sum16(o0);
        o1 = group_sum16(o1);
        if (lane == 0) {
            outp[(size_t)i * 2 + 0] = o0 + bout[0];
            outp[(size_t)i * 2 + 1] = o1 + bout[1];
        }
    } else {
        if (grp == 0) *(float4*)&hout[(size_t)i * 64 + sub * 4] = res;
    }
}

// ---------------- launch ----------------

extern "C" void kernel_launch(void* const* d_in, const int* in_sizes, int n_in,
                              void* d_out, int out_size, void* d_ws, size_t ws_size,
                              hipStream_t stream) {
    const float* x    = (const float*)d_in[0];
    const int*   ei   = (const int*)d_in[1];   // [2][E]: row0=src, row1=dst
    const float* Wl   = (const float*)d_in[2];
    const float* bl   = (const float*)d_in[3];
    const float* Wr   = (const float*)d_in[4];
    const float* br   = (const float*)d_in[5];
    const float* att  = (const float*)d_in[6];
    const float* bg   = (const float*)d_in[7];
    const float* Ws   = (const float*)d_in[8];
    const float* bs   = (const float*)d_in[9];
    const float* Wout = (const float*)d_in[10];
    const float* bout = (const float*)d_in[11];
    float* out = (float*)d_out;

    size_t off = 0;
    char* base = (char*)d_ws;
    auto alloc = [&](size_t bytes) -> void* {
        void* p = base + off;
        off += (bytes + 255) & ~(size_t)255;
        return p;
    };
    float* Xl     = (float*)alloc((size_t)NN * 64 * 4);
    float* XRS    = (float*)alloc((size_t)NN * 128 * 4);
    float* h      = (float*)alloc((size_t)NN * 64 * 4);
    int*   cnt    = (int*)alloc((size_t)NN * 4);
    int*   headA  = (int*)alloc((size_t)NN * 4);
    int*   nextA  = (int*)alloc((size_t)EE * 4);
    int*   offs   = (int*)alloc((size_t)(NN + 1) * 4);
    int*   csr    = (int*)alloc((size_t)EE * 4);
    int*   part   = (int*)alloc(512 * 4);

    const int* src = ei;
    const int* dst = ei + EE;

    hipMemsetAsync(headA, 0xFF, (size_t)NN * 4, stream);   // -1
    build_kernel<<<(EE + 255) / 256, 256, 0, stream>>>(dst, headA, nextA);
    count_walk<<<NB, 256, 0, stream>>>(headA, nextA, cnt);
    scan1<<<NB, 256, 0, stream>>>(cnt, part);
    scan2<<<1, 512, 0, stream>>>(part);
    scan3<<<NB, 256, 0, stream>>>(cnt, part, offs);
    walk_kernel<<<NB, 256, 0, stream>>>(headA, nextA, src, offs, csr);

    const float* hin = x;
    for (int L = 0; L < 3; L++) {
        gemm_fused<<<(NN + 63) / 64, 512, 0, stream>>>(
            hin, Wl + L * 4096, Wr + L * 4096, Ws + L * 4096,
            bl + L * 64, br + L * 64, bs + L * 64, Xl, XRS);
        node_kernel<<<NN / 4, 256, 0, stream>>>(
            Xl, XRS, offs, csr, att + L * 64, bg + L * 64, h, (L < 2) ? 1 : 0,
            Wout, bout, out, (L == 2) ? 1 : 0);
        hin = h;
    }
}

// Round 9
// 499.528 us; speedup vs baseline: 1.6283x; 1.0312x over previous
//
#include <hip/hip_runtime.h>
#include <stdint.h>

#define NN 100000
#define EE 1600000
#define DD 64
#define NB 391   // ceil(NN/256)

using short8 = __attribute__((ext_vector_type(8))) short;
using f32x4  = __attribute__((ext_vector_type(4))) float;

// ---------------- bf16 split helpers ----------------

__device__ __forceinline__ unsigned short bf16_rne(float f) {
    unsigned int u = __float_as_uint(f);
    unsigned int r = (u + 0x7FFFu + ((u >> 16) & 1u)) >> 16;
    return (unsigned short)r;
}
__device__ __forceinline__ float bf16_to_f32(unsigned short h) {
    return __uint_as_float(((unsigned int)h) << 16);
}

// ---------------- CSR build via linked lists (single atomic per edge) ----------------

__global__ void build_kernel(const int* __restrict__ dst,
                             int* __restrict__ head, int* __restrict__ next) {
    int e = blockIdx.x * blockDim.x + threadIdx.x;
    if (e < EE) {
        next[e] = atomicExch(&head[dst[e]], e);
    }
}

__global__ void count_walk(const int* __restrict__ head, const int* __restrict__ next,
                           int* __restrict__ cnt) {
    int i = blockIdx.x * 256 + threadIdx.x;
    if (i >= NN) return;
    int c = 0;
    for (int p = head[i]; p >= 0; p = next[p]) c++;
    cnt[i] = c;
}

__global__ void scan1(const int* __restrict__ cnt, int* __restrict__ partial) {
    __shared__ int s[256];
    int i = blockIdx.x * 256 + threadIdx.x;
    int v = (i < NN) ? cnt[i] : 0;
    s[threadIdx.x] = v;
    __syncthreads();
    for (int off = 128; off > 0; off >>= 1) {
        if (threadIdx.x < off) s[threadIdx.x] += s[threadIdx.x + off];
        __syncthreads();
    }
    if (threadIdx.x == 0) partial[blockIdx.x] = s[0];
}

__global__ void scan2(int* __restrict__ partial) {
    __shared__ int s[512];
    int t = threadIdx.x;
    int v = (t < NB) ? partial[t] : 0;
    s[t] = v;
    __syncthreads();
    for (int off = 1; off < 512; off <<= 1) {
        int add = (t >= off) ? s[t - off] : 0;
        __syncthreads();
        s[t] += add;
        __syncthreads();
    }
    if (t < NB) partial[t] = s[t] - v;  // exclusive
}

__global__ void scan3(const int* __restrict__ cnt, const int* __restrict__ partial,
                      int* __restrict__ offsets) {
    __shared__ int s[256];
    int t = threadIdx.x;
    int i = blockIdx.x * 256 + t;
    int v = (i < NN) ? cnt[i] : 0;
    s[t] = v;
    __syncthreads();
    for (int off = 1; off < 256; off <<= 1) {
        int add = (t >= off) ? s[t - off] : 0;
        __syncthreads();
        s[t] += add;
        __syncthreads();
    }
    int excl = s[t] - v + partial[blockIdx.x];
    if (i < NN) {
        offsets[i] = excl;
        if (i == NN - 1) offsets[NN] = excl + v;
    }
}

__global__ void walk_kernel(const int* __restrict__ head, const int* __restrict__ next,
                            const int* __restrict__ srcA, const int* __restrict__ offsets,
                            int* __restrict__ csr) {
    int i = blockIdx.x * 256 + threadIdx.x;
    if (i >= NN) return;
    int p = head[i];
    int w = offsets[i];
    while (p >= 0) {
        csr[w++] = srcA[p];
        p = next[p];
    }
}

// ---------------- weight conversion: W[L][k][n] -> Wt_hi/lo[(L*3+j)][n][k] bf16 ----------------
// 9 matrices of 64x64 (3 layers x {Wl,Wr,Ws}), transposed so B-fragments are contiguous in k.

__global__ void conv_w(const float* __restrict__ Wl, const float* __restrict__ Wr,
                       const float* __restrict__ Ws,
                       unsigned short* __restrict__ Wt_hi, unsigned short* __restrict__ Wt_lo) {
    int e = blockIdx.x * 256 + threadIdx.x;
    if (e >= 9 * 4096) return;
    int mat = e >> 12;          // 0..8 = L*3 + j
    int r   = e & 4095;
    int k   = r >> 6, n = r & 63;
    int L = mat / 3, j = mat % 3;
    const float* W = (j == 0) ? Wl : ((j == 1) ? Wr : Ws);
    float v = W[L * 4096 + k * 64 + n];
    unsigned short hi = bf16_rne(v);
    unsigned short lo = bf16_rne(v - bf16_to_f32(hi));
    Wt_hi[mat * 4096 + n * 64 + k] = hi;
    Wt_lo[mat * 4096 + n * 64 + k] = lo;
}

// ---------------- x conversion: f32 -> hi/lo bf16 planes ----------------

__global__ void conv_x(const float* __restrict__ x,
                       unsigned short* __restrict__ Ahi, unsigned short* __restrict__ Alo) {
    int i = blockIdx.x * 256 + threadIdx.x;           // one float4 per thread
    int total = NN * 16;
    for (; i < total; i += gridDim.x * 256) {
        float4 v = *(const float4*)&x[(size_t)i * 4];
        ushort4 h, l;
        h.x = bf16_rne(v.x); l.x = bf16_rne(v.x - bf16_to_f32(h.x));
        h.y = bf16_rne(v.y); l.y = bf16_rne(v.y - bf16_to_f32(h.y));
        h.z = bf16_rne(v.z); l.z = bf16_rne(v.z - bf16_to_f32(h.z));
        h.w = bf16_rne(v.w); l.w = bf16_rne(v.w - bf16_to_f32(h.w));
        *(ushort4*)&Ahi[(size_t)i * 4] = h;
        *(ushort4*)&Alo[(size_t)i * 4] = l;
    }
}

// ---------------- MFMA GEMM via split-bf16: C = A@W for 3 mats, fp32-accurate ----------------
// A ~ Ahi + Alo, W ~ Whi + Wlo;  C = Ahi*Whi + Ahi*Wlo + Alo*Whi  (lo*lo dropped, ~3e-5).
// mfma_f32_16x16x32_bf16 layouts (m89/m91-verified C/D; A/B per AMD calculator):
//   A: m = lane&15, k = (lane>>4)*8 + i  -> 16B contiguous load from A[m][k..k+7]
//   B: n = lane&15, k = (lane>>4)*8 + i  -> 16B contiguous load from Wt[n][k..k+7]
//   D: col = lane&15, row = (lane>>4)*4 + reg
// No LDS; weights are L2-resident (48KB/layer). Each wave: 16 rows, A-frags loaded once.

__global__ __launch_bounds__(256) void gemm_mfma(
    const unsigned short* __restrict__ Ahi, const unsigned short* __restrict__ Alo,
    const unsigned short* __restrict__ Wt_hi, const unsigned short* __restrict__ Wt_lo,
    const float* __restrict__ bl, const float* __restrict__ br, const float* __restrict__ bs,
    float* __restrict__ Xl, float* __restrict__ XRS) {
    int lane = threadIdx.x & 63;
    int wid  = threadIdx.x >> 6;
    int m0 = (blockIdx.x * 4 + wid) * 16;
    if (m0 >= NN) return;

    int arow = m0 + (lane & 15);
    if (arow >= NN) arow = NN - 1;                    // clamp (stores guarded)
    int koff = (lane >> 4) * 8;

    const unsigned short* abase = Ahi + (size_t)arow * 64;
    const unsigned short* lbase = Alo + (size_t)arow * 64;
    short8 ahi0 = *(const short8*)(abase + koff);
    short8 ahi1 = *(const short8*)(abase + 32 + koff);
    short8 alo0 = *(const short8*)(lbase + koff);
    short8 alo1 = *(const short8*)(lbase + 32 + koff);

    int col16 = lane & 15;
    int r0 = m0 + ((lane >> 4) << 2);                 // first of 4 output rows

#pragma unroll
    for (int m = 0; m < 3; m++) {
        const unsigned short* wh = Wt_hi + m * 4096;
        const unsigned short* wl = Wt_lo + m * 4096;
        const float* bias = (m == 0) ? bl : ((m == 1) ? br : bs);
#pragma unroll
        for (int tt = 0; tt < 4; tt++) {
            int ncol = tt * 16 + col16;
            const unsigned short* bh = wh + ncol * 64 + koff;
            const unsigned short* blo = wl + ncol * 64 + koff;
            short8 bhi0 = *(const short8*)bh;
            short8 bhi1 = *(const short8*)(bh + 32);
            short8 blo0 = *(const short8*)blo;
            short8 blo1 = *(const short8*)(blo + 32);

            f32x4 acc = {0.f, 0.f, 0.f, 0.f};
            acc = __builtin_amdgcn_mfma_f32_16x16x32_bf16(ahi0, bhi0, acc, 0, 0, 0);
            acc = __builtin_amdgcn_mfma_f32_16x16x32_bf16(ahi1, bhi1, acc, 0, 0, 0);
            acc = __builtin_amdgcn_mfma_f32_16x16x32_bf16(ahi0, blo0, acc, 0, 0, 0);
            acc = __builtin_amdgcn_mfma_f32_16x16x32_bf16(ahi1, blo1, acc, 0, 0, 0);
            acc = __builtin_amdgcn_mfma_f32_16x16x32_bf16(alo0, bhi0, acc, 0, 0, 0);
            acc = __builtin_amdgcn_mfma_f32_16x16x32_bf16(alo1, bhi1, acc, 0, 0, 0);

            float bb = bias[ncol];
#pragma unroll
            for (int j = 0; j < 4; j++) {
                int row = r0 + j;
                if (row < NN) {
                    float v = acc[j] + bb;
                    if (m == 0)      Xl[(size_t)row * 64 + ncol]        = v;
                    else if (m == 1) XRS[(size_t)row * 128 + ncol]      = v;
                    else             XRS[(size_t)row * 128 + 64 + ncol] = v;
                }
            }
        }
    }
}

// ---------------- per-node attention aggregation ----------------

__device__ __forceinline__ float group_sum16(float t) {
    t += __int_as_float(__builtin_amdgcn_update_dpp(0, __float_as_int(t), 0xB1, 0xF, 0xF, true));   // xor1
    t += __int_as_float(__builtin_amdgcn_update_dpp(0, __float_as_int(t), 0x4E, 0xF, 0xF, true));   // xor2
    t += __int_as_float(__builtin_amdgcn_update_dpp(0, __float_as_int(t), 0x141, 0xF, 0xF, true));  // row_half_mirror ~ xor4
    t += __int_as_float(__builtin_amdgcn_update_dpp(0, __float_as_int(t), 0x140, 0xF, 0xF, true));  // row_mirror ~ xor8
    return t;
}

__device__ __forceinline__ float lrelu(float v) {
    return (v > 0.f) ? v : 0.2f * v;
}

__global__ __launch_bounds__(256) void node_kernel(
    const float* __restrict__ Xl, const float* __restrict__ XRS,
    const int* __restrict__ offsets, const int* __restrict__ csr,
    const float* __restrict__ att, const float* __restrict__ bg,
    unsigned short* __restrict__ houtHi, unsigned short* __restrict__ houtLo, int do_relu,
    const float* __restrict__ Wout, const float* __restrict__ bout,
    float* __restrict__ outp, int do_out) {
    int lane = threadIdx.x & 63;
    int wid  = threadIdx.x >> 6;
    int i = blockIdx.x * 4 + wid;
    if (i >= NN) return;
    int sub = lane & 15;
    int grp = lane >> 4;

    float4 xr4  = *(const float4*)&XRS[(size_t)i * 128 + sub * 4];
    float4 att4 = *(const float4*)&att[sub * 4];

    float aggx = 0.f, aggy = 0.f, aggz = 0.f, aggw = 0.f;
    float denom = 0.f;
    int beg = offsets[i], end = offsets[i + 1];

    for (int j0 = beg; j0 < end; j0 += 8) {
        int jA = j0 + grp, jB = j0 + grp + 4;
        bool vA = jA < end, vB = jB < end;
        int sA = csr[vA ? jA : beg];
        int sB = csr[vB ? jB : beg];
        float4 xA = *(const float4*)&Xl[(size_t)sA * 64 + sub * 4];
        float4 xB = *(const float4*)&Xl[(size_t)sB * 64 + sub * 4];

        float tA = lrelu(xA.x + xr4.x) * att4.x + lrelu(xA.y + xr4.y) * att4.y
                 + lrelu(xA.z + xr4.z) * att4.z + lrelu(xA.w + xr4.w) * att4.w;
        float tB = lrelu(xB.x + xr4.x) * att4.x + lrelu(xB.y + xr4.y) * att4.y
                 + lrelu(xB.z + xr4.z) * att4.z + lrelu(xB.w + xr4.w) * att4.w;
        tA = group_sum16(tA);
        tB = group_sum16(tB);
        float aA = vA ? __expf(tA) : 0.f;
        float aB = vB ? __expf(tB) : 0.f;

        aggx += aA * xA.x + aB * xB.x;
        aggy += aA * xA.y + aB * xB.y;
        aggz += aA * xA.z + aB * xB.z;
        aggw += aA * xA.w + aB * xB.w;
        denom += aA + aB;
    }

#pragma unroll
    for (int m = 16; m <= 32; m <<= 1) {
        aggx  += __shfl_xor(aggx, m, 64);
        aggy  += __shfl_xor(aggy, m, 64);
        aggz  += __shfl_xor(aggz, m, 64);
        aggw  += __shfl_xor(aggw, m, 64);
        denom += __shfl_xor(denom, m, 64);
    }

    float inv = (denom > 0.f) ? (1.0f / denom) : 0.f;
    float4 sk4 = *(const float4*)&XRS[(size_t)i * 128 + 64 + sub * 4];
    float4 bg4 = *(const float4*)&bg[sub * 4];
    float4 res;
    res.x = aggx * inv + bg4.x + sk4.x;
    res.y = aggy * inv + bg4.y + sk4.y;
    res.z = aggz * inv + bg4.z + sk4.z;
    res.w = aggw * inv + bg4.w + sk4.w;
    if (do_relu) {
        res.x = fmaxf(res.x, 0.f); res.y = fmaxf(res.y, 0.f);
        res.z = fmaxf(res.z, 0.f); res.w = fmaxf(res.w, 0.f);
    }
    if (do_out) {
        float4 w01 = *(const float4*)&Wout[8 * sub];
        float4 w23 = *(const float4*)&Wout[8 * sub + 4];
        float o0 = res.x * w01.x + res.y * w01.z + res.z * w23.x + res.w * w23.z;
        float o1 = res.x * w01.y + res.y * w01.w + res.z * w23.y + res.w * w23.w;
        o0 = group_sum16(o0);
        o1 = group_sum16(o1);
        if (lane == 0) {
            outp[(size_t)i * 2 + 0] = o0 + bout[0];
            outp[(size_t)i * 2 + 1] = o1 + bout[1];
        }
    } else {
        if (grp == 0) {
            ushort4 h, l;
            h.x = bf16_rne(res.x); l.x = bf16_rne(res.x - bf16_to_f32(h.x));
            h.y = bf16_rne(res.y); l.y = bf16_rne(res.y - bf16_to_f32(h.y));
            h.z = bf16_rne(res.z); l.z = bf16_rne(res.z - bf16_to_f32(h.z));
            h.w = bf16_rne(res.w); l.w = bf16_rne(res.w - bf16_to_f32(h.w));
            *(ushort4*)&houtHi[(size_t)i * 64 + sub * 4] = h;
            *(ushort4*)&houtLo[(size_t)i * 64 + sub * 4] = l;
        }
    }
}

// ---------------- launch ----------------

extern "C" void kernel_launch(void* const* d_in, const int* in_sizes, int n_in,
                              void* d_out, int out_size, void* d_ws, size_t ws_size,
                              hipStream_t stream) {
    const float* x    = (const float*)d_in[0];
    const int*   ei   = (const int*)d_in[1];
    const float* Wl   = (const float*)d_in[2];
    const float* bl   = (const float*)d_in[3];
    const float* Wr   = (const float*)d_in[4];
    const float* br   = (const float*)d_in[5];
    const float* att  = (const float*)d_in[6];
    const float* bg   = (const float*)d_in[7];
    const float* Ws   = (const float*)d_in[8];
    const float* bs   = (const float*)d_in[9];
    const float* Wout = (const float*)d_in[10];
    const float* bout = (const float*)d_in[11];
    float* out = (float*)d_out;

    size_t off = 0;
    char* base = (char*)d_ws;
    auto alloc = [&](size_t bytes) -> void* {
        void* p = base + off;
        off += (bytes + 255) & ~(size_t)255;
        return p;
    };
    float* Xl   = (float*)alloc((size_t)NN * 64 * 4);
    float* XRS  = (float*)alloc((size_t)NN * 128 * 4);
    unsigned short* Ahi = (unsigned short*)alloc((size_t)NN * 64 * 2);
    unsigned short* Alo = (unsigned short*)alloc((size_t)NN * 64 * 2);
    unsigned short* Bhi = (unsigned short*)alloc((size_t)NN * 64 * 2);
    unsigned short* Blo = (unsigned short*)alloc((size_t)NN * 64 * 2);
    unsigned short* Wthi = (unsigned short*)alloc((size_t)9 * 4096 * 2);
    unsigned short* Wtlo = (unsigned short*)alloc((size_t)9 * 4096 * 2);
    int* cnt   = (int*)alloc((size_t)NN * 4);
    int* headA = (int*)alloc((size_t)NN * 4);
    int* nextA = (int*)alloc((size_t)EE * 4);
    int* offs  = (int*)alloc((size_t)(NN + 1) * 4);
    int* csr   = (int*)alloc((size_t)EE * 4);
    int* part  = (int*)alloc(512 * 4);

    const int* src = ei;
    const int* dst = ei + EE;

    hipMemsetAsync(headA, 0xFF, (size_t)NN * 4, stream);
    build_kernel<<<(EE + 255) / 256, 256, 0, stream>>>(dst, headA, nextA);
    count_walk<<<NB, 256, 0, stream>>>(headA, nextA, cnt);
    scan1<<<NB, 256, 0, stream>>>(cnt, part);
    scan2<<<1, 512, 0, stream>>>(part);
    scan3<<<NB, 256, 0, stream>>>(cnt, part, offs);
    walk_kernel<<<NB, 256, 0, stream>>>(headA, nextA, src, offs, csr);

    conv_w<<<(9 * 4096 + 255) / 256, 256, 0, stream>>>(Wl, Wr, Ws, Wthi, Wtlo);
    conv_x<<<2048, 256, 0, stream>>>(x, Ahi, Alo);

    unsigned short* curHi = Ahi; unsigned short* curLo = Alo;
    unsigned short* nxtHi = Bhi; unsigned short* nxtLo = Blo;
    for (int L = 0; L < 3; L++) {
        gemm_mfma<<<(NN + 63) / 64, 256, 0, stream>>>(
            curHi, curLo, Wthi + (size_t)L * 3 * 4096, Wtlo + (size_t)L * 3 * 4096,
            bl + L * 64, br + L * 64, bs + L * 64, Xl, XRS);
        node_kernel<<<NN / 4, 256, 0, stream>>>(
            Xl, XRS, offs, csr, att + L * 64, bg + L * 64,
            nxtHi, nxtLo, (L < 2) ? 1 : 0,
            Wout, bout, out, (L == 2) ? 1 : 0);
        unsigned short* th = curHi; curHi = nxtHi; nxtHi = th;
        unsigned short* tl = curLo; curLo = nxtLo; nxtLo = tl;
    }
}

// Round 10
// 476.165 us; speedup vs baseline: 1.7082x; 1.0491x over previous
//
#include <hip/hip_runtime.h>
#include <stdint.h>

#define NN 100000
#define EE 1600000
#define DD 64
#define NB 391   // ceil(NN/256)

using short8 = __attribute__((ext_vector_type(8))) short;
using f32x4  = __attribute__((ext_vector_type(4))) float;
using f2     = __attribute__((ext_vector_type(2))) float;

// ---------------- bf16 split helpers ----------------

__device__ __forceinline__ unsigned short bf16_rne(float f) {
    unsigned int u = __float_as_uint(f);
    unsigned int r = (u + 0x7FFFu + ((u >> 16) & 1u)) >> 16;
    return (unsigned short)r;
}
__device__ __forceinline__ float bf16_to_f32(unsigned short h) {
    return __uint_as_float(((unsigned int)h) << 16);
}

// ---------------- CSR build via linked lists (single atomic per edge) ----------------
// nexts[e] = (prev_head, src[e]) packed: walk does ONE 8B random load per edge.

__global__ void build_kernel(const int* __restrict__ src, const int* __restrict__ dst,
                             int* __restrict__ head, int2* __restrict__ nexts) {
    int e = blockIdx.x * blockDim.x + threadIdx.x;
    if (e < EE) {
        int2 v;
        v.x = atomicExch(&head[dst[e]], e);
        v.y = src[e];
        nexts[e] = v;
    }
}

// scan1 fused with chain-length count
__global__ void scan1(const int* __restrict__ head, const int2* __restrict__ nexts,
                      int* __restrict__ cnt, int* __restrict__ partial) {
    __shared__ int s[256];
    int i = blockIdx.x * 256 + threadIdx.x;
    int v = 0;
    if (i < NN) {
        for (int p = head[i]; p >= 0; p = nexts[p].x) v++;
        cnt[i] = v;
    }
    s[threadIdx.x] = v;
    __syncthreads();
    for (int off = 128; off > 0; off >>= 1) {
        if (threadIdx.x < off) s[threadIdx.x] += s[threadIdx.x + off];
        __syncthreads();
    }
    if (threadIdx.x == 0) partial[blockIdx.x] = s[0];
}

__global__ void scan2(int* __restrict__ partial) {
    __shared__ int s[512];
    int t = threadIdx.x;
    int v = (t < NB) ? partial[t] : 0;
    s[t] = v;
    __syncthreads();
    for (int off = 1; off < 512; off <<= 1) {
        int add = (t >= off) ? s[t - off] : 0;
        __syncthreads();
        s[t] += add;
        __syncthreads();
    }
    if (t < NB) partial[t] = s[t] - v;  // exclusive
}

// scan3 fused with csr emission (walks chain writing contiguous csr)
__global__ void scan3(const int* __restrict__ cnt, const int* __restrict__ partial,
                      const int* __restrict__ head, const int2* __restrict__ nexts,
                      int* __restrict__ offsets, int* __restrict__ csr) {
    __shared__ int s[256];
    int t = threadIdx.x;
    int i = blockIdx.x * 256 + t;
    int v = (i < NN) ? cnt[i] : 0;
    s[t] = v;
    __syncthreads();
    for (int off = 1; off < 256; off <<= 1) {
        int add = (t >= off) ? s[t - off] : 0;
        __syncthreads();
        s[t] += add;
        __syncthreads();
    }
    int excl = s[t] - v + partial[blockIdx.x];
    if (i < NN) {
        offsets[i] = excl;
        if (i == NN - 1) offsets[NN] = excl + v;
        int w = excl;
        for (int p = head[i]; p >= 0;) {
            int2 nv = nexts[p];
            csr[w++] = nv.y;
            p = nv.x;
        }
    }
}

// ---------------- weight conversion: W[L][k][n] -> Wt_hi/lo[(L*3+j)][n][k] bf16 ----------------

__global__ void conv_w(const float* __restrict__ Wl, const float* __restrict__ Wr,
                       const float* __restrict__ Ws,
                       unsigned short* __restrict__ Wt_hi, unsigned short* __restrict__ Wt_lo) {
    int e = blockIdx.x * 256 + threadIdx.x;
    if (e >= 9 * 4096) return;
    int mat = e >> 12;          // 0..8 = L*3 + j
    int r   = e & 4095;
    int k   = r >> 6, n = r & 63;
    int L = mat / 3, j = mat % 3;
    const float* W = (j == 0) ? Wl : ((j == 1) ? Wr : Ws);
    float v = W[L * 4096 + k * 64 + n];
    unsigned short hi = bf16_rne(v);
    unsigned short lo = bf16_rne(v - bf16_to_f32(hi));
    Wt_hi[mat * 4096 + n * 64 + k] = hi;
    Wt_lo[mat * 4096 + n * 64 + k] = lo;
}

// ---------------- x conversion: f32 -> hi/lo bf16 planes ----------------

__global__ void conv_x(const float* __restrict__ x,
                       unsigned short* __restrict__ Ahi, unsigned short* __restrict__ Alo) {
    int i = blockIdx.x * 256 + threadIdx.x;           // one float4 per thread
    int total = NN * 16;
    for (; i < total; i += gridDim.x * 256) {
        float4 v = *(const float4*)&x[(size_t)i * 4];
        ushort4 h, l;
        h.x = bf16_rne(v.x); l.x = bf16_rne(v.x - bf16_to_f32(h.x));
        h.y = bf16_rne(v.y); l.y = bf16_rne(v.y - bf16_to_f32(h.y));
        h.z = bf16_rne(v.z); l.z = bf16_rne(v.z - bf16_to_f32(h.z));
        h.w = bf16_rne(v.w); l.w = bf16_rne(v.w - bf16_to_f32(h.w));
        *(ushort4*)&Ahi[(size_t)i * 4] = h;
        *(ushort4*)&Alo[(size_t)i * 4] = l;
    }
}

// ---------------- MFMA GEMM via split-bf16 (unchanged from R9) ----------------

__global__ __launch_bounds__(256) void gemm_mfma(
    const unsigned short* __restrict__ Ahi, const unsigned short* __restrict__ Alo,
    const unsigned short* __restrict__ Wt_hi, const unsigned short* __restrict__ Wt_lo,
    const float* __restrict__ bl, const float* __restrict__ br, const float* __restrict__ bs,
    float* __restrict__ Xl, float* __restrict__ XRS) {
    int lane = threadIdx.x & 63;
    int wid  = threadIdx.x >> 6;
    int m0 = (blockIdx.x * 4 + wid) * 16;
    if (m0 >= NN) return;

    int arow = m0 + (lane & 15);
    if (arow >= NN) arow = NN - 1;                    // clamp (stores guarded)
    int koff = (lane >> 4) * 8;

    const unsigned short* abase = Ahi + (size_t)arow * 64;
    const unsigned short* lbase = Alo + (size_t)arow * 64;
    short8 ahi0 = *(const short8*)(abase + koff);
    short8 ahi1 = *(const short8*)(abase + 32 + koff);
    short8 alo0 = *(const short8*)(lbase + koff);
    short8 alo1 = *(const short8*)(lbase + 32 + koff);

    int col16 = lane & 15;
    int r0 = m0 + ((lane >> 4) << 2);                 // first of 4 output rows

#pragma unroll
    for (int m = 0; m < 3; m++) {
        const unsigned short* wh = Wt_hi + m * 4096;
        const unsigned short* wl = Wt_lo + m * 4096;
        const float* bias = (m == 0) ? bl : ((m == 1) ? br : bs);
#pragma unroll
        for (int tt = 0; tt < 4; tt++) {
            int ncol = tt * 16 + col16;
            const unsigned short* bh = wh + ncol * 64 + koff;
            const unsigned short* blo = wl + ncol * 64 + koff;
            short8 bhi0 = *(const short8*)bh;
            short8 bhi1 = *(const short8*)(bh + 32);
            short8 blo0 = *(const short8*)blo;
            short8 blo1 = *(const short8*)(blo + 32);

            f32x4 acc = {0.f, 0.f, 0.f, 0.f};
            acc = __builtin_amdgcn_mfma_f32_16x16x32_bf16(ahi0, bhi0, acc, 0, 0, 0);
            acc = __builtin_amdgcn_mfma_f32_16x16x32_bf16(ahi1, bhi1, acc, 0, 0, 0);
            acc = __builtin_amdgcn_mfma_f32_16x16x32_bf16(ahi0, blo0, acc, 0, 0, 0);
            acc = __builtin_amdgcn_mfma_f32_16x16x32_bf16(ahi1, blo1, acc, 0, 0, 0);
            acc = __builtin_amdgcn_mfma_f32_16x16x32_bf16(alo0, bhi0, acc, 0, 0, 0);
            acc = __builtin_amdgcn_mfma_f32_16x16x32_bf16(alo1, bhi1, acc, 0, 0, 0);

            float bb = bias[ncol];
#pragma unroll
            for (int j = 0; j < 4; j++) {
                int row = r0 + j;
                if (row < NN) {
                    float v = acc[j] + bb;
                    if (m == 0)      Xl[(size_t)row * 64 + ncol]        = v;
                    else if (m == 1) XRS[(size_t)row * 128 + ncol]      = v;
                    else             XRS[(size_t)row * 128 + 64 + ncol] = v;
                }
            }
        }
    }
}

// ---------------- per-node attention aggregation ----------------
// One wave per dst node; 4 edges in parallel, 16 lanes per edge.
// Core arithmetic on float2 ext-vectors to enable v_pk_{add,mul,fma}_f32 dual-issue.

__device__ __forceinline__ float group_sum16(float t) {
    t += __int_as_float(__builtin_amdgcn_update_dpp(0, __float_as_int(t), 0xB1, 0xF, 0xF, true));   // xor1
    t += __int_as_float(__builtin_amdgcn_update_dpp(0, __float_as_int(t), 0x4E, 0xF, 0xF, true));   // xor2
    t += __int_as_float(__builtin_amdgcn_update_dpp(0, __float_as_int(t), 0x141, 0xF, 0xF, true));  // row_half_mirror ~ xor4
    t += __int_as_float(__builtin_amdgcn_update_dpp(0, __float_as_int(t), 0x140, 0xF, 0xF, true));  // row_mirror ~ xor8
    return t;
}

__global__ __launch_bounds__(256) void node_kernel(
    const float* __restrict__ Xl, const float* __restrict__ XRS,
    const int* __restrict__ offsets, const int* __restrict__ csr,
    const float* __restrict__ att, const float* __restrict__ bg,
    unsigned short* __restrict__ houtHi, unsigned short* __restrict__ houtLo, int do_relu,
    const float* __restrict__ Wout, const float* __restrict__ bout,
    float* __restrict__ outp, int do_out) {
    int lane = threadIdx.x & 63;
    int wid  = threadIdx.x >> 6;
    int i = blockIdx.x * 4 + wid;
    if (i >= NN) return;
    int sub = lane & 15;
    int grp = lane >> 4;

    float4 xr4  = *(const float4*)&XRS[(size_t)i * 128 + sub * 4];
    float4 att4 = *(const float4*)&att[sub * 4];
    f2 xr01 = {xr4.x, xr4.y}, xr23 = {xr4.z, xr4.w};
    f2 at01 = {att4.x, att4.y}, at23 = {att4.z, att4.w};

    f2 agg01 = {0.f, 0.f}, agg23 = {0.f, 0.f};
    float denom = 0.f;
    int beg = offsets[i], end = offsets[i + 1];

    for (int j0 = beg; j0 < end; j0 += 8) {
        int jA = j0 + grp, jB = j0 + grp + 4;
        bool vA = jA < end, vB = jB < end;
        int sA = csr[vA ? jA : beg];
        int sB = csr[vB ? jB : beg];
        float4 xA = *(const float4*)&Xl[(size_t)sA * 64 + sub * 4];
        float4 xB = *(const float4*)&Xl[(size_t)sB * 64 + sub * 4];
        f2 xA01 = {xA.x, xA.y}, xA23 = {xA.z, xA.w};
        f2 xB01 = {xB.x, xB.y}, xB23 = {xB.z, xB.w};

        f2 sA01 = xA01 + xr01;                 // v_pk_add_f32
        f2 sA23 = xA23 + xr23;
        f2 sB01 = xB01 + xr01;
        f2 sB23 = xB23 + xr23;
        // lrelu = max(v, 0.2v): scalar mul+max per component (no pk f32 max)
        f2 lA01 = { fmaxf(sA01.x, 0.2f * sA01.x), fmaxf(sA01.y, 0.2f * sA01.y) };
        f2 lA23 = { fmaxf(sA23.x, 0.2f * sA23.x), fmaxf(sA23.y, 0.2f * sA23.y) };
        f2 lB01 = { fmaxf(sB01.x, 0.2f * sB01.x), fmaxf(sB01.y, 0.2f * sB01.y) };
        f2 lB23 = { fmaxf(sB23.x, 0.2f * sB23.x), fmaxf(sB23.y, 0.2f * sB23.y) };

        f2 tAv = lA01 * at01 + lA23 * at23;    // pk_mul + pk_fma
        f2 tBv = lB01 * at01 + lB23 * at23;
        float tA = group_sum16(tAv.x + tAv.y);
        float tB = group_sum16(tBv.x + tBv.y);
        float aA = vA ? __expf(tA) : 0.f;
        float aB = vB ? __expf(tB) : 0.f;

        f2 aAv = {aA, aA};
        f2 aBv = {aB, aB};
        agg01 += aAv * xA01 + aBv * xB01;      // pk_fma chain
        agg23 += aAv * xA23 + aBv * xB23;
        denom += aA + aB;
    }

    // combine the 4 edge groups (once per node)
    float aggx = agg01.x, aggy = agg01.y, aggz = agg23.x, aggw = agg23.y;
#pragma unroll
    for (int m = 16; m <= 32; m <<= 1) {
        aggx  += __shfl_xor(aggx, m, 64);
        aggy  += __shfl_xor(aggy, m, 64);
        aggz  += __shfl_xor(aggz, m, 64);
        aggw  += __shfl_xor(aggw, m, 64);
        denom += __shfl_xor(denom, m, 64);
    }

    float inv = (denom > 0.f) ? (1.0f / denom) : 0.f;
    float4 sk4 = *(const float4*)&XRS[(size_t)i * 128 + 64 + sub * 4];
    float4 bg4 = *(const float4*)&bg[sub * 4];
    float4 res;
    res.x = aggx * inv + bg4.x + sk4.x;
    res.y = aggy * inv + bg4.y + sk4.y;
    res.z = aggz * inv + bg4.z + sk4.z;
    res.w = aggw * inv + bg4.w + sk4.w;
    if (do_relu) {
        res.x = fmaxf(res.x, 0.f); res.y = fmaxf(res.y, 0.f);
        res.z = fmaxf(res.z, 0.f); res.w = fmaxf(res.w, 0.f);
    }
    if (do_out) {
        float4 w01 = *(const float4*)&Wout[8 * sub];
        float4 w23 = *(const float4*)&Wout[8 * sub + 4];
        float o0 = res.x * w01.x + res.y * w01.z + res.z * w23.x + res.w * w23.z;
        float o1 = res.x * w01.y + res.y * w01.w + res.z * w23.y + res.w * w23.w;
        o0 = group_sum16(o0);
        o1 = group_sum16(o1);
        if (lane == 0) {
            outp[(size_t)i * 2 + 0] = o0 + bout[0];
            outp[(size_t)i * 2 + 1] = o1 + bout[1];
        }
    } else {
        if (grp == 0) {
            ushort4 h, l;
            h.x = bf16_rne(res.x); l.x = bf16_rne(res.x - bf16_to_f32(h.x));
            h.y = bf16_rne(res.y); l.y = bf16_rne(res.y - bf16_to_f32(h.y));
            h.z = bf16_rne(res.z); l.z = bf16_rne(res.z - bf16_to_f32(h.z));
            h.w = bf16_rne(res.w); l.w = bf16_rne(res.w - bf16_to_f32(h.w));
            *(ushort4*)&houtHi[(size_t)i * 64 + sub * 4] = h;
            *(ushort4*)&houtLo[(size_t)i * 64 + sub * 4] = l;
        }
    }
}

// ---------------- launch ----------------

extern "C" void kernel_launch(void* const* d_in, const int* in_sizes, int n_in,
                              void* d_out, int out_size, void* d_ws, size_t ws_size,
                              hipStream_t stream) {
    const float* x    = (const float*)d_in[0];
    const int*   ei   = (const int*)d_in[1];
    const float* Wl   = (const float*)d_in[2];
    const float* bl   = (const float*)d_in[3];
    const float* Wr   = (const float*)d_in[4];
    const float* br   = (const float*)d_in[5];
    const float* att  = (const float*)d_in[6];
    const float* bg   = (const float*)d_in[7];
    const float* Ws   = (const float*)d_in[8];
    const float* bs   = (const float*)d_in[9];
    const float* Wout = (const float*)d_in[10];
    const float* bout = (const float*)d_in[11];
    float* out = (float*)d_out;

    size_t off = 0;
    char* base = (char*)d_ws;
    auto alloc = [&](size_t bytes) -> void* {
        void* p = base + off;
        off += (bytes + 255) & ~(size_t)255;
        return p;
    };
    float* Xl   = (float*)alloc((size_t)NN * 64 * 4);
    float* XRS  = (float*)alloc((size_t)NN * 128 * 4);
    unsigned short* Ahi = (unsigned short*)alloc((size_t)NN * 64 * 2);
    unsigned short* Alo = (unsigned short*)alloc((size_t)NN * 64 * 2);
    unsigned short* Bhi = (unsigned short*)alloc((size_t)NN * 64 * 2);
    unsigned short* Blo = (unsigned short*)alloc((size_t)NN * 64 * 2);
    unsigned short* Wthi = (unsigned short*)alloc((size_t)9 * 4096 * 2);
    unsigned short* Wtlo = (unsigned short*)alloc((size_t)9 * 4096 * 2);
    int*  cnt   = (int*)alloc((size_t)NN * 4);
    int*  headA = (int*)alloc((size_t)NN * 4);
    int2* nexts = (int2*)alloc((size_t)EE * 8);
    int*  offs  = (int*)alloc((size_t)(NN + 1) * 4);
    int*  csr   = (int*)alloc((size_t)EE * 4);
    int*  part  = (int*)alloc(512 * 4);

    const int* src = ei;
    const int* dst = ei + EE;

    hipMemsetAsync(headA, 0xFF, (size_t)NN * 4, stream);
    build_kernel<<<(EE + 255) / 256, 256, 0, stream>>>(src, dst, headA, nexts);
    scan1<<<NB, 256, 0, stream>>>(headA, nexts, cnt, part);
    scan2<<<1, 512, 0, stream>>>(part);
    scan3<<<NB, 256, 0, stream>>>(cnt, part, headA, nexts, offs, csr);

    conv_w<<<(9 * 4096 + 255) / 256, 256, 0, stream>>>(Wl, Wr, Ws, Wthi, Wtlo);
    conv_x<<<2048, 256, 0, stream>>>(x, Ahi, Alo);

    unsigned short* curHi = Ahi; unsigned short* curLo = Alo;
    unsigned short* nxtHi = Bhi; unsigned short* nxtLo = Blo;
    for (int L = 0; L < 3; L++) {
        gemm_mfma<<<(NN + 63) / 64, 256, 0, stream>>>(
            curHi, curLo, Wthi + (size_t)L * 3 * 4096, Wtlo + (size_t)L * 3 * 4096,
            bl + L * 64, br + L * 64, bs + L * 64, Xl, XRS);
        node_kernel<<<NN / 4, 256, 0, stream>>>(
            Xl, XRS, offs, csr, att + L * 64, bg + L * 64,
            nxtHi, nxtLo, (L < 2) ? 1 : 0,
            Wout, bout, out, (L == 2) ? 1 : 0);
        unsigned short* th = curHi; curHi = nxtHi; nxtHi = th;
        unsigned short* tl = curLo; curLo = nxtLo; nxtLo = tl;
    }
}

// Round 11
// 413.235 us; speedup vs baseline: 1.9683x; 1.1523x over previous
//
#include <hip/hip_runtime.h>
#include <stdint.h>

#define NN 100000
#define EE 1600000
#define DD 64
#define NBUCK 391        // ceil(NN/256): bucket b covers nodes [b*256, b*256+255]
#define SCWG 200         // scatter workgroups; 8000 edges each
#define SCCHUNK 8000

using short8 = __attribute__((ext_vector_type(8))) short;
using f32x4  = __attribute__((ext_vector_type(4))) float;
using f2     = __attribute__((ext_vector_type(2))) float;

// ---------------- bf16 split helpers ----------------

__device__ __forceinline__ unsigned short bf16_rne(float f) {
    unsigned int u = __float_as_uint(f);
    unsigned int r = (u + 0x7FFFu + ((u >> 16) & 1u)) >> 16;
    return (unsigned short)r;
}
__device__ __forceinline__ float bf16_to_f32(unsigned short h) {
    return __uint_as_float(((unsigned int)h) << 16);
}

// ---------------- CSR build via bucketed counting sort (LDS atomics only in hot path) ----------------

__global__ void bucket_hist(const int* __restrict__ dst, int* __restrict__ bhist) {
    __shared__ int h[NBUCK];
    int t = threadIdx.x;
    for (int b = t; b < NBUCK; b += 256) h[b] = 0;
    __syncthreads();
    int start = blockIdx.x * SCCHUNK;
    int endi = min(start + SCCHUNK, EE);
    for (int e = start + t; e < endi; e += 256)
        atomicAdd(&h[dst[e] >> 8], 1);
    __syncthreads();
    for (int b = t; b < NBUCK; b += 256)
        if (h[b]) atomicAdd(&bhist[b], h[b]);
}

__global__ void bucket_scan(const int* __restrict__ bhist, int* __restrict__ bbase,
                            int* __restrict__ bcursor, int* __restrict__ offsets) {
    __shared__ int s[512];
    int t = threadIdx.x;
    int v = (t < NBUCK) ? bhist[t] : 0;
    s[t] = v;
    __syncthreads();
    for (int off = 1; off < 512; off <<= 1) {
        int a = (t >= off) ? s[t - off] : 0;
        __syncthreads();
        s[t] += a;
        __syncthreads();
    }
    if (t < NBUCK) { int excl = s[t] - v; bbase[t] = excl; bcursor[t] = excl; }
    if (t == 0) { bbase[NBUCK] = EE; offsets[NN] = EE; }
}

// scatter (dst,src) into bucket-grouped array; per-wg contiguous runs per bucket
__global__ void bucket_scatter(const int* __restrict__ src, const int* __restrict__ dst,
                               int* __restrict__ bcursor, int2* __restrict__ bedges) {
    __shared__ int cnt[NBUCK];
    __shared__ int lcur[NBUCK];
    int t = threadIdx.x;
    for (int b = t; b < NBUCK; b += 256) cnt[b] = 0;
    __syncthreads();
    int start = blockIdx.x * SCCHUNK;
    int endi = min(start + SCCHUNK, EE);
    for (int e = start + t; e < endi; e += 256)
        atomicAdd(&cnt[dst[e] >> 8], 1);
    __syncthreads();
    for (int b = t; b < NBUCK; b += 256) {
        int c = cnt[b];
        lcur[b] = c ? atomicAdd(&bcursor[b], c) : 0;   // reserve contiguous run
    }
    __syncthreads();
    for (int e = start + t; e < endi; e += 256) {
        int d = dst[e];
        int pos = atomicAdd(&lcur[d >> 8], 1);
        int2 v; v.x = d; v.y = src[e];
        bedges[pos] = v;
    }
}

// one wg per bucket: node-level counting sort within the bucket -> offsets + csr
__global__ void bucket_csr(const int2* __restrict__ bedges, const int* __restrict__ bbase,
                           int* __restrict__ offsets, int* __restrict__ csr) {
    __shared__ int ncnt[256];
    __shared__ int lofs[256];
    int b = blockIdx.x;
    int t = threadIdx.x;
    int beg = bbase[b], endb = bbase[b + 1];
    ncnt[t] = 0;
    __syncthreads();
    for (int e = beg + t; e < endb; e += 256)
        atomicAdd(&ncnt[bedges[e].x & 255], 1);
    __syncthreads();
    int v = ncnt[t];
    lofs[t] = v;
    __syncthreads();
    for (int off = 1; off < 256; off <<= 1) {
        int a = (t >= off) ? lofs[t - off] : 0;
        __syncthreads();
        lofs[t] += a;
        __syncthreads();
    }
    int excl = lofs[t] - v;
    int node = b * 256 + t;
    if (node < NN) offsets[node] = beg + excl;
    __syncthreads();
    ncnt[t] = beg + excl;                  // reuse as cursor
    __syncthreads();
    for (int e = beg + t; e < endb; e += 256) {
        int2 ed = bedges[e];
        int pos = atomicAdd(&ncnt[ed.x & 255], 1);
        csr[pos] = ed.y;
    }
}

// ---------------- weight conversion: W[L][k][n] -> Wt_hi/lo[(L*3+j)][n][k] bf16 ----------------

__global__ void conv_w(const float* __restrict__ Wl, const float* __restrict__ Wr,
                       const float* __restrict__ Ws,
                       unsigned short* __restrict__ Wt_hi, unsigned short* __restrict__ Wt_lo) {
    int e = blockIdx.x * 256 + threadIdx.x;
    if (e >= 9 * 4096) return;
    int mat = e >> 12;          // 0..8 = L*3 + j
    int r   = e & 4095;
    int k   = r >> 6, n = r & 63;
    int L = mat / 3, j = mat % 3;
    const float* W = (j == 0) ? Wl : ((j == 1) ? Wr : Ws);
    float v = W[L * 4096 + k * 64 + n];
    unsigned short hi = bf16_rne(v);
    unsigned short lo = bf16_rne(v - bf16_to_f32(hi));
    Wt_hi[mat * 4096 + n * 64 + k] = hi;
    Wt_lo[mat * 4096 + n * 64 + k] = lo;
}

// ---------------- x conversion: f32 -> hi/lo bf16 planes ----------------

__global__ void conv_x(const float* __restrict__ x,
                       unsigned short* __restrict__ Ahi, unsigned short* __restrict__ Alo) {
    int i = blockIdx.x * 256 + threadIdx.x;           // one float4 per thread
    int total = NN * 16;
    for (; i < total; i += gridDim.x * 256) {
        float4 v = *(const float4*)&x[(size_t)i * 4];
        ushort4 h, l;
        h.x = bf16_rne(v.x); l.x = bf16_rne(v.x - bf16_to_f32(h.x));
        h.y = bf16_rne(v.y); l.y = bf16_rne(v.y - bf16_to_f32(h.y));
        h.z = bf16_rne(v.z); l.z = bf16_rne(v.z - bf16_to_f32(h.z));
        h.w = bf16_rne(v.w); l.w = bf16_rne(v.w - bf16_to_f32(h.w));
        *(ushort4*)&Ahi[(size_t)i * 4] = h;
        *(ushort4*)&Alo[(size_t)i * 4] = l;
    }
}

// ---------------- MFMA GEMM via split-bf16 ----------------

__global__ __launch_bounds__(256) void gemm_mfma(
    const unsigned short* __restrict__ Ahi, const unsigned short* __restrict__ Alo,
    const unsigned short* __restrict__ Wt_hi, const unsigned short* __restrict__ Wt_lo,
    const float* __restrict__ bl, const float* __restrict__ br, const float* __restrict__ bs,
    float* __restrict__ Xl, float* __restrict__ XRS) {
    int lane = threadIdx.x & 63;
    int wid  = threadIdx.x >> 6;
    int m0 = (blockIdx.x * 4 + wid) * 16;
    if (m0 >= NN) return;

    int arow = m0 + (lane & 15);
    if (arow >= NN) arow = NN - 1;                    // clamp (stores guarded)
    int koff = (lane >> 4) * 8;

    const unsigned short* abase = Ahi + (size_t)arow * 64;
    const unsigned short* lbase = Alo + (size_t)arow * 64;
    short8 ahi0 = *(const short8*)(abase + koff);
    short8 ahi1 = *(const short8*)(abase + 32 + koff);
    short8 alo0 = *(const short8*)(lbase + koff);
    short8 alo1 = *(const short8*)(lbase + 32 + koff);

    int col16 = lane & 15;
    int r0 = m0 + ((lane >> 4) << 2);                 // first of 4 output rows

#pragma unroll
    for (int m = 0; m < 3; m++) {
        const unsigned short* wh = Wt_hi + m * 4096;
        const unsigned short* wl = Wt_lo + m * 4096;
        const float* bias = (m == 0) ? bl : ((m == 1) ? br : bs);
#pragma unroll
        for (int tt = 0; tt < 4; tt++) {
            int ncol = tt * 16 + col16;
            const unsigned short* bh = wh + ncol * 64 + koff;
            const unsigned short* blo = wl + ncol * 64 + koff;
            short8 bhi0 = *(const short8*)bh;
            short8 bhi1 = *(const short8*)(bh + 32);
            short8 blo0 = *(const short8*)blo;
            short8 blo1 = *(const short8*)(blo + 32);

            f32x4 acc = {0.f, 0.f, 0.f, 0.f};
            acc = __builtin_amdgcn_mfma_f32_16x16x32_bf16(ahi0, bhi0, acc, 0, 0, 0);
            acc = __builtin_amdgcn_mfma_f32_16x16x32_bf16(ahi1, bhi1, acc, 0, 0, 0);
            acc = __builtin_amdgcn_mfma_f32_16x16x32_bf16(ahi0, blo0, acc, 0, 0, 0);
            acc = __builtin_amdgcn_mfma_f32_16x16x32_bf16(ahi1, blo1, acc, 0, 0, 0);
            acc = __builtin_amdgcn_mfma_f32_16x16x32_bf16(alo0, bhi0, acc, 0, 0, 0);
            acc = __builtin_amdgcn_mfma_f32_16x16x32_bf16(alo1, bhi1, acc, 0, 0, 0);

            float bb = bias[ncol];
#pragma unroll
            for (int j = 0; j < 4; j++) {
                int row = r0 + j;
                if (row < NN) {
                    float v = acc[j] + bb;
                    if (m == 0)      Xl[(size_t)row * 64 + ncol]        = v;
                    else if (m == 1) XRS[(size_t)row * 128 + ncol]      = v;
                    else             XRS[(size_t)row * 128 + 64 + ncol] = v;
                }
            }
        }
    }
}

// ---------------- per-node attention aggregation ----------------

__device__ __forceinline__ float group_sum16(float t) {
    t += __int_as_float(__builtin_amdgcn_update_dpp(0, __float_as_int(t), 0xB1, 0xF, 0xF, true));   // xor1
    t += __int_as_float(__builtin_amdgcn_update_dpp(0, __float_as_int(t), 0x4E, 0xF, 0xF, true));   // xor2
    t += __int_as_float(__builtin_amdgcn_update_dpp(0, __float_as_int(t), 0x141, 0xF, 0xF, true));  // row_half_mirror ~ xor4
    t += __int_as_float(__builtin_amdgcn_update_dpp(0, __float_as_int(t), 0x140, 0xF, 0xF, true));  // row_mirror ~ xor8
    return t;
}

__global__ __launch_bounds__(256) void node_kernel(
    const float* __restrict__ Xl, const float* __restrict__ XRS,
    const int* __restrict__ offsets, const int* __restrict__ csr,
    const float* __restrict__ att, const float* __restrict__ bg,
    unsigned short* __restrict__ houtHi, unsigned short* __restrict__ houtLo, int do_relu,
    const float* __restrict__ Wout, const float* __restrict__ bout,
    float* __restrict__ outp, int do_out) {
    int lane = threadIdx.x & 63;
    int wid  = threadIdx.x >> 6;
    int i = blockIdx.x * 4 + wid;
    if (i >= NN) return;
    int sub = lane & 15;
    int grp = lane >> 4;

    float4 xr4  = *(const float4*)&XRS[(size_t)i * 128 + sub * 4];
    float4 att4 = *(const float4*)&att[sub * 4];
    f2 xr01 = {xr4.x, xr4.y}, xr23 = {xr4.z, xr4.w};
    f2 at01 = {att4.x, att4.y}, at23 = {att4.z, att4.w};

    f2 agg01 = {0.f, 0.f}, agg23 = {0.f, 0.f};
    float denom = 0.f;
    int beg = offsets[i], end = offsets[i + 1];

    for (int j0 = beg; j0 < end; j0 += 8) {
        int jA = j0 + grp, jB = j0 + grp + 4;
        bool vA = jA < end, vB = jB < end;
        int sA = csr[vA ? jA : beg];
        int sB = csr[vB ? jB : beg];
        float4 xA = *(const float4*)&Xl[(size_t)sA * 64 + sub * 4];
        float4 xB = *(const float4*)&Xl[(size_t)sB * 64 + sub * 4];
        f2 xA01 = {xA.x, xA.y}, xA23 = {xA.z, xA.w};
        f2 xB01 = {xB.x, xB.y}, xB23 = {xB.z, xB.w};

        f2 sA01 = xA01 + xr01;                 // v_pk_add_f32
        f2 sA23 = xA23 + xr23;
        f2 sB01 = xB01 + xr01;
        f2 sB23 = xB23 + xr23;
        f2 lA01 = { fmaxf(sA01.x, 0.2f * sA01.x), fmaxf(sA01.y, 0.2f * sA01.y) };
        f2 lA23 = { fmaxf(sA23.x, 0.2f * sA23.x), fmaxf(sA23.y, 0.2f * sA23.y) };
        f2 lB01 = { fmaxf(sB01.x, 0.2f * sB01.x), fmaxf(sB01.y, 0.2f * sB01.y) };
        f2 lB23 = { fmaxf(sB23.x, 0.2f * sB23.x), fmaxf(sB23.y, 0.2f * sB23.y) };

        f2 tAv = lA01 * at01 + lA23 * at23;    // pk_mul + pk_fma
        f2 tBv = lB01 * at01 + lB23 * at23;
        float tA = group_sum16(tAv.x + tAv.y);
        float tB = group_sum16(tBv.x + tBv.y);
        float aA = vA ? __expf(tA) : 0.f;
        float aB = vB ? __expf(tB) : 0.f;

        f2 aAv = {aA, aA};
        f2 aBv = {aB, aB};
        agg01 += aAv * xA01 + aBv * xB01;      // pk_fma chain
        agg23 += aAv * xA23 + aBv * xB23;
        denom += aA + aB;
    }

    float aggx = agg01.x, aggy = agg01.y, aggz = agg23.x, aggw = agg23.y;
#pragma unroll
    for (int m = 16; m <= 32; m <<= 1) {
        aggx  += __shfl_xor(aggx, m, 64);
        aggy  += __shfl_xor(aggy, m, 64);
        aggz  += __shfl_xor(aggz, m, 64);
        aggw  += __shfl_xor(aggw, m, 64);
        denom += __shfl_xor(denom, m, 64);
    }

    float inv = (denom > 0.f) ? (1.0f / denom) : 0.f;
    float4 sk4 = *(const float4*)&XRS[(size_t)i * 128 + 64 + sub * 4];
    float4 bg4 = *(const float4*)&bg[sub * 4];
    float4 res;
    res.x = aggx * inv + bg4.x + sk4.x;
    res.y = aggy * inv + bg4.y + sk4.y;
    res.z = aggz * inv + bg4.z + sk4.z;
    res.w = aggw * inv + bg4.w + sk4.w;
    if (do_relu) {
        res.x = fmaxf(res.x, 0.f); res.y = fmaxf(res.y, 0.f);
        res.z = fmaxf(res.z, 0.f); res.w = fmaxf(res.w, 0.f);
    }
    if (do_out) {
        float4 w01 = *(const float4*)&Wout[8 * sub];
        float4 w23 = *(const float4*)&Wout[8 * sub + 4];
        float o0 = res.x * w01.x + res.y * w01.z + res.z * w23.x + res.w * w23.z;
        float o1 = res.x * w01.y + res.y * w01.w + res.z * w23.y + res.w * w23.w;
        o0 = group_sum16(o0);
        o1 = group_sum16(o1);
        if (lane == 0) {
            outp[(size_t)i * 2 + 0] = o0 + bout[0];
            outp[(size_t)i * 2 + 1] = o1 + bout[1];
        }
    } else {
        if (grp == 0) {
            ushort4 h, l;
            h.x = bf16_rne(res.x); l.x = bf16_rne(res.x - bf16_to_f32(h.x));
            h.y = bf16_rne(res.y); l.y = bf16_rne(res.y - bf16_to_f32(h.y));
            h.z = bf16_rne(res.z); l.z = bf16_rne(res.z - bf16_to_f32(h.z));
            h.w = bf16_rne(res.w); l.w = bf16_rne(res.w - bf16_to_f32(h.w));
            *(ushort4*)&houtHi[(size_t)i * 64 + sub * 4] = h;
            *(ushort4*)&houtLo[(size_t)i * 64 + sub * 4] = l;
        }
    }
}

// ---------------- launch ----------------

extern "C" void kernel_launch(void* const* d_in, const int* in_sizes, int n_in,
                              void* d_out, int out_size, void* d_ws, size_t ws_size,
                              hipStream_t stream) {
    const float* x    = (const float*)d_in[0];
    const int*   ei   = (const int*)d_in[1];
    const float* Wl   = (const float*)d_in[2];
    const float* bl   = (const float*)d_in[3];
    const float* Wr   = (const float*)d_in[4];
    const float* br   = (const float*)d_in[5];
    const float* att  = (const float*)d_in[6];
    const float* bg   = (const float*)d_in[7];
    const float* Ws   = (const float*)d_in[8];
    const float* bs   = (const float*)d_in[9];
    const float* Wout = (const float*)d_in[10];
    const float* bout = (const float*)d_in[11];
    float* out = (float*)d_out;

    size_t off = 0;
    char* base = (char*)d_ws;
    auto alloc = [&](size_t bytes) -> void* {
        void* p = base + off;
        off += (bytes + 255) & ~(size_t)255;
        return p;
    };
    float* Xl   = (float*)alloc((size_t)NN * 64 * 4);
    float* XRS  = (float*)alloc((size_t)NN * 128 * 4);
    unsigned short* Ahi = (unsigned short*)alloc((size_t)NN * 64 * 2);
    unsigned short* Alo = (unsigned short*)alloc((size_t)NN * 64 * 2);
    unsigned short* Bhi = (unsigned short*)alloc((size_t)NN * 64 * 2);
    unsigned short* Blo = (unsigned short*)alloc((size_t)NN * 64 * 2);
    unsigned short* Wthi = (unsigned short*)alloc((size_t)9 * 4096 * 2);
    unsigned short* Wtlo = (unsigned short*)alloc((size_t)9 * 4096 * 2);
    int*  bhist  = (int*)alloc((size_t)NBUCK * 4);
    int*  bbase  = (int*)alloc((size_t)(NBUCK + 1) * 4);
    int*  bcur   = (int*)alloc((size_t)NBUCK * 4);
    int2* bedges = (int2*)alloc((size_t)EE * 8);
    int*  offs   = (int*)alloc((size_t)(NN + 1) * 4);
    int*  csr    = (int*)alloc((size_t)EE * 4);

    const int* src = ei;
    const int* dst = ei + EE;

    hipMemsetAsync(bhist, 0, (size_t)NBUCK * 4, stream);
    bucket_hist<<<SCWG, 256, 0, stream>>>(dst, bhist);
    bucket_scan<<<1, 512, 0, stream>>>(bhist, bbase, bcur, offs);
    bucket_scatter<<<SCWG, 256, 0, stream>>>(src, dst, bcur, bedges);
    bucket_csr<<<NBUCK, 256, 0, stream>>>(bedges, bbase, offs, csr);

    conv_w<<<(9 * 4096 + 255) / 256, 256, 0, stream>>>(Wl, Wr, Ws, Wthi, Wtlo);
    conv_x<<<2048, 256, 0, stream>>>(x, Ahi, Alo);

    unsigned short* curHi = Ahi; unsigned short* curLo = Alo;
    unsigned short* nxtHi = Bhi; unsigned short* nxtLo = Blo;
    for (int L = 0; L < 3; L++) {
        gemm_mfma<<<(NN + 63) / 64, 256, 0, stream>>>(
            curHi, curLo, Wthi + (size_t)L * 3 * 4096, Wtlo + (size_t)L * 3 * 4096,
            bl + L * 64, br + L * 64, bs + L * 64, Xl, XRS);
        node_kernel<<<NN / 4, 256, 0, stream>>>(
            Xl, XRS, offs, csr, att + L * 64, bg + L * 64,
            nxtHi, nxtLo, (L < 2) ? 1 : 0,
            Wout, bout, out, (L == 2) ? 1 : 0);
        unsigned short* th = curHi; curHi = nxtHi; nxtHi = th;
        unsigned short* tl = curLo; curLo = nxtLo; nxtLo = tl;
    }
}

// Round 12
// 382.167 us; speedup vs baseline: 2.1283x; 1.0813x over previous
//
#include <hip/hip_runtime.h>
#include <stdint.h>

#define NN 100000
#define EE 1600000
#define DD 64
#define NBUCK 391        // ceil(NN/256): bucket b covers nodes [b*256, b*256+255]
#define SCWG 200         // scatter workgroups; 8000 edges each
#define SCCHUNK 8000

using short8 = __attribute__((ext_vector_type(8))) short;
using f32x4  = __attribute__((ext_vector_type(4))) float;
using f2     = __attribute__((ext_vector_type(2))) float;

// ---------------- bf16 split helpers ----------------

__device__ __forceinline__ unsigned short bf16_rne(float f) {
    unsigned int u = __float_as_uint(f);
    unsigned int r = (u + 0x7FFFu + ((u >> 16) & 1u)) >> 16;
    return (unsigned short)r;
}
__device__ __forceinline__ float bf16_to_f32(unsigned short h) {
    return __uint_as_float(((unsigned int)h) << 16);
}

// ---------------- CSR build via bucketed counting sort (LDS atomics only in hot path) ----------------
// bedges packs (dst&255)<<24 | src  (src < 2^24): 4B per edge.

__global__ void bucket_hist(const int* __restrict__ dst, int* __restrict__ bhist) {
    __shared__ int h[NBUCK];
    int t = threadIdx.x;
    for (int b = t; b < NBUCK; b += 256) h[b] = 0;
    __syncthreads();
    int start = blockIdx.x * SCCHUNK;
    int endi = min(start + SCCHUNK, EE);
    for (int e = start + t; e < endi; e += 256)
        atomicAdd(&h[dst[e] >> 8], 1);
    __syncthreads();
    for (int b = t; b < NBUCK; b += 256)
        if (h[b]) atomicAdd(&bhist[b], h[b]);
}

__global__ void bucket_scan(const int* __restrict__ bhist, int* __restrict__ bbase,
                            int* __restrict__ bcursor, int* __restrict__ offsets) {
    __shared__ int s[512];
    int t = threadIdx.x;
    int v = (t < NBUCK) ? bhist[t] : 0;
    s[t] = v;
    __syncthreads();
    for (int off = 1; off < 512; off <<= 1) {
        int a = (t >= off) ? s[t - off] : 0;
        __syncthreads();
        s[t] += a;
        __syncthreads();
    }
    if (t < NBUCK) { int excl = s[t] - v; bbase[t] = excl; bcursor[t] = excl; }
    if (t == 0) { bbase[NBUCK] = EE; offsets[NN] = EE; }
}

__global__ void bucket_scatter(const int* __restrict__ src, const int* __restrict__ dst,
                               int* __restrict__ bcursor, unsigned int* __restrict__ bedges) {
    __shared__ int cnt[NBUCK];
    __shared__ int lcur[NBUCK];
    int t = threadIdx.x;
    for (int b = t; b < NBUCK; b += 256) cnt[b] = 0;
    __syncthreads();
    int start = blockIdx.x * SCCHUNK;
    int endi = min(start + SCCHUNK, EE);
    for (int e = start + t; e < endi; e += 256)
        atomicAdd(&cnt[dst[e] >> 8], 1);
    __syncthreads();
    for (int b = t; b < NBUCK; b += 256) {
        int c = cnt[b];
        lcur[b] = c ? atomicAdd(&bcursor[b], c) : 0;   // reserve contiguous run
    }
    __syncthreads();
    for (int e = start + t; e < endi; e += 256) {
        int d = dst[e];
        int pos = atomicAdd(&lcur[d >> 8], 1);
        bedges[pos] = ((unsigned int)(d & 255) << 24) | (unsigned int)src[e];
    }
}

__global__ void bucket_csr(const unsigned int* __restrict__ bedges, const int* __restrict__ bbase,
                           int* __restrict__ offsets, int* __restrict__ csr) {
    __shared__ int ncnt[256];
    __shared__ int lofs[256];
    int b = blockIdx.x;
    int t = threadIdx.x;
    int beg = bbase[b], endb = bbase[b + 1];
    ncnt[t] = 0;
    __syncthreads();
    for (int e = beg + t; e < endb; e += 256)
        atomicAdd(&ncnt[bedges[e] >> 24], 1);
    __syncthreads();
    int v = ncnt[t];
    lofs[t] = v;
    __syncthreads();
    for (int off = 1; off < 256; off <<= 1) {
        int a = (t >= off) ? lofs[t - off] : 0;
        __syncthreads();
        lofs[t] += a;
        __syncthreads();
    }
    int excl = lofs[t] - v;
    int node = b * 256 + t;
    if (node < NN) offsets[node] = beg + excl;
    __syncthreads();
    ncnt[t] = beg + excl;                  // reuse as cursor
    __syncthreads();
    for (int e = beg + t; e < endb; e += 256) {
        unsigned int ed = bedges[e];
        int pos = atomicAdd(&ncnt[ed >> 24], 1);
        csr[pos] = (int)(ed & 0xFFFFFFu);
    }
}

// ---------------- weight conversion: W[L][k][n] -> Wt_hi/lo[(L*3+j)][n][k] bf16 ----------------

__global__ void conv_w(const float* __restrict__ Wl, const float* __restrict__ Wr,
                       const float* __restrict__ Ws,
                       unsigned short* __restrict__ Wt_hi, unsigned short* __restrict__ Wt_lo) {
    int e = blockIdx.x * 256 + threadIdx.x;
    if (e >= 9 * 4096) return;
    int mat = e >> 12;          // 0..8 = L*3 + j
    int r   = e & 4095;
    int k   = r >> 6, n = r & 63;
    int L = mat / 3, j = mat % 3;
    const float* W = (j == 0) ? Wl : ((j == 1) ? Wr : Ws);
    float v = W[L * 4096 + k * 64 + n];
    unsigned short hi = bf16_rne(v);
    unsigned short lo = bf16_rne(v - bf16_to_f32(hi));
    Wt_hi[mat * 4096 + n * 64 + k] = hi;
    Wt_lo[mat * 4096 + n * 64 + k] = lo;
}

// ---------------- x conversion: f32 -> hi/lo bf16 planes ----------------

__global__ void conv_x(const float* __restrict__ x,
                       unsigned short* __restrict__ Ahi, unsigned short* __restrict__ Alo) {
    int i = blockIdx.x * 256 + threadIdx.x;           // one float4 per thread
    int total = NN * 16;
    for (; i < total; i += gridDim.x * 256) {
        float4 v = *(const float4*)&x[(size_t)i * 4];
        ushort4 h, l;
        h.x = bf16_rne(v.x); l.x = bf16_rne(v.x - bf16_to_f32(h.x));
        h.y = bf16_rne(v.y); l.y = bf16_rne(v.y - bf16_to_f32(h.y));
        h.z = bf16_rne(v.z); l.z = bf16_rne(v.z - bf16_to_f32(h.z));
        h.w = bf16_rne(v.w); l.w = bf16_rne(v.w - bf16_to_f32(h.w));
        *(ushort4*)&Ahi[(size_t)i * 4] = h;
        *(ushort4*)&Alo[(size_t)i * 4] = l;
    }
}

// ---------------- MFMA GEMM via split-bf16; Xl output is bf16 (gather target) ----------------

__global__ __launch_bounds__(256) void gemm_mfma(
    const unsigned short* __restrict__ Ahi, const unsigned short* __restrict__ Alo,
    const unsigned short* __restrict__ Wt_hi, const unsigned short* __restrict__ Wt_lo,
    const float* __restrict__ bl, const float* __restrict__ br, const float* __restrict__ bs,
    unsigned short* __restrict__ Xlb, float* __restrict__ XRS) {
    int lane = threadIdx.x & 63;
    int wid  = threadIdx.x >> 6;
    int m0 = (blockIdx.x * 4 + wid) * 16;
    if (m0 >= NN) return;

    int arow = m0 + (lane & 15);
    if (arow >= NN) arow = NN - 1;                    // clamp (stores guarded)
    int koff = (lane >> 4) * 8;

    const unsigned short* abase = Ahi + (size_t)arow * 64;
    const unsigned short* lbase = Alo + (size_t)arow * 64;
    short8 ahi0 = *(const short8*)(abase + koff);
    short8 ahi1 = *(const short8*)(abase + 32 + koff);
    short8 alo0 = *(const short8*)(lbase + koff);
    short8 alo1 = *(const short8*)(lbase + 32 + koff);

    int col16 = lane & 15;
    int r0 = m0 + ((lane >> 4) << 2);                 // first of 4 output rows

#pragma unroll
    for (int m = 0; m < 3; m++) {
        const unsigned short* wh = Wt_hi + m * 4096;
        const unsigned short* wl = Wt_lo + m * 4096;
        const float* bias = (m == 0) ? bl : ((m == 1) ? br : bs);
#pragma unroll
        for (int tt = 0; tt < 4; tt++) {
            int ncol = tt * 16 + col16;
            const unsigned short* bh = wh + ncol * 64 + koff;
            const unsigned short* blo = wl + ncol * 64 + koff;
            short8 bhi0 = *(const short8*)bh;
            short8 bhi1 = *(const short8*)(bh + 32);
            short8 blo0 = *(const short8*)blo;
            short8 blo1 = *(const short8*)(blo + 32);

            f32x4 acc = {0.f, 0.f, 0.f, 0.f};
            acc = __builtin_amdgcn_mfma_f32_16x16x32_bf16(ahi0, bhi0, acc, 0, 0, 0);
            acc = __builtin_amdgcn_mfma_f32_16x16x32_bf16(ahi1, bhi1, acc, 0, 0, 0);
            acc = __builtin_amdgcn_mfma_f32_16x16x32_bf16(ahi0, blo0, acc, 0, 0, 0);
            acc = __builtin_amdgcn_mfma_f32_16x16x32_bf16(ahi1, blo1, acc, 0, 0, 0);
            acc = __builtin_amdgcn_mfma_f32_16x16x32_bf16(alo0, bhi0, acc, 0, 0, 0);
            acc = __builtin_amdgcn_mfma_f32_16x16x32_bf16(alo1, bhi1, acc, 0, 0, 0);

            float bb = bias[ncol];
#pragma unroll
            for (int j = 0; j < 4; j++) {
                int row = r0 + j;
                if (row < NN) {
                    float v = acc[j] + bb;
                    if (m == 0)      Xlb[(size_t)row * 64 + ncol]       = bf16_rne(v);
                    else if (m == 1) XRS[(size_t)row * 128 + ncol]      = v;
                    else             XRS[(size_t)row * 128 + 64 + ncol] = v;
                }
            }
        }
    }
}

// ---------------- per-node attention aggregation ----------------
// Gather target Xlb is bf16: 8B/lane random loads, unpack via shift/mask (free bit-ops).

__device__ __forceinline__ float group_sum16(float t) {
    t += __int_as_float(__builtin_amdgcn_update_dpp(0, __float_as_int(t), 0xB1, 0xF, 0xF, true));   // xor1
    t += __int_as_float(__builtin_amdgcn_update_dpp(0, __float_as_int(t), 0x4E, 0xF, 0xF, true));   // xor2
    t += __int_as_float(__builtin_amdgcn_update_dpp(0, __float_as_int(t), 0x141, 0xF, 0xF, true));  // row_half_mirror ~ xor4
    t += __int_as_float(__builtin_amdgcn_update_dpp(0, __float_as_int(t), 0x140, 0xF, 0xF, true));  // row_mirror ~ xor8
    return t;
}

__global__ __launch_bounds__(256) void node_kernel(
    const unsigned short* __restrict__ Xlb, const float* __restrict__ XRS,
    const int* __restrict__ offsets, const int* __restrict__ csr,
    const float* __restrict__ att, const float* __restrict__ bg,
    unsigned short* __restrict__ houtHi, unsigned short* __restrict__ houtLo, int do_relu,
    const float* __restrict__ Wout, const float* __restrict__ bout,
    float* __restrict__ outp, int do_out) {
    int lane = threadIdx.x & 63;
    int wid  = threadIdx.x >> 6;
    int i = blockIdx.x * 4 + wid;
    if (i >= NN) return;
    int sub = lane & 15;
    int grp = lane >> 4;

    float4 xr4  = *(const float4*)&XRS[(size_t)i * 128 + sub * 4];
    float4 att4 = *(const float4*)&att[sub * 4];
    f2 xr01 = {xr4.x, xr4.y}, xr23 = {xr4.z, xr4.w};
    f2 at01 = {att4.x, att4.y}, at23 = {att4.z, att4.w};

    f2 agg01 = {0.f, 0.f}, agg23 = {0.f, 0.f};
    float denom = 0.f;
    int beg = offsets[i], end = offsets[i + 1];

    for (int j0 = beg; j0 < end; j0 += 8) {
        int jA = j0 + grp, jB = j0 + grp + 4;
        bool vA = jA < end, vB = jB < end;
        int sA = csr[vA ? jA : beg];
        int sB = csr[vB ? jB : beg];
        uint2 uA = *(const uint2*)&Xlb[(size_t)sA * 64 + sub * 4];
        uint2 uB = *(const uint2*)&Xlb[(size_t)sB * 64 + sub * 4];
        f2 xA01 = { __uint_as_float(uA.x << 16), __uint_as_float(uA.x & 0xFFFF0000u) };
        f2 xA23 = { __uint_as_float(uA.y << 16), __uint_as_float(uA.y & 0xFFFF0000u) };
        f2 xB01 = { __uint_as_float(uB.x << 16), __uint_as_float(uB.x & 0xFFFF0000u) };
        f2 xB23 = { __uint_as_float(uB.y << 16), __uint_as_float(uB.y & 0xFFFF0000u) };

        f2 sA01 = xA01 + xr01;                 // v_pk_add_f32
        f2 sA23 = xA23 + xr23;
        f2 sB01 = xB01 + xr01;
        f2 sB23 = xB23 + xr23;
        f2 lA01 = { fmaxf(sA01.x, 0.2f * sA01.x), fmaxf(sA01.y, 0.2f * sA01.y) };
        f2 lA23 = { fmaxf(sA23.x, 0.2f * sA23.x), fmaxf(sA23.y, 0.2f * sA23.y) };
        f2 lB01 = { fmaxf(sB01.x, 0.2f * sB01.x), fmaxf(sB01.y, 0.2f * sB01.y) };
        f2 lB23 = { fmaxf(sB23.x, 0.2f * sB23.x), fmaxf(sB23.y, 0.2f * sB23.y) };

        f2 tAv = lA01 * at01 + lA23 * at23;    // pk_mul + pk_fma
        f2 tBv = lB01 * at01 + lB23 * at23;
        float tA = group_sum16(tAv.x + tAv.y);
        float tB = group_sum16(tBv.x + tBv.y);
        float aA = vA ? __expf(tA) : 0.f;
        float aB = vB ? __expf(tB) : 0.f;

        f2 aAv = {aA, aA};
        f2 aBv = {aB, aB};
        agg01 += aAv * xA01 + aBv * xB01;      // pk_fma chain
        agg23 += aAv * xA23 + aBv * xB23;
        denom += aA + aB;
    }

    float aggx = agg01.x, aggy = agg01.y, aggz = agg23.x, aggw = agg23.y;
#pragma unroll
    for (int m = 16; m <= 32; m <<= 1) {
        aggx  += __shfl_xor(aggx, m, 64);
        aggy  += __shfl_xor(aggy, m, 64);
        aggz  += __shfl_xor(aggz, m, 64);
        aggw  += __shfl_xor(aggw, m, 64);
        denom += __shfl_xor(denom, m, 64);
    }

    float inv = (denom > 0.f) ? (1.0f / denom) : 0.f;
    float4 sk4 = *(const float4*)&XRS[(size_t)i * 128 + 64 + sub * 4];
    float4 bg4 = *(const float4*)&bg[sub * 4];
    float4 res;
    res.x = aggx * inv + bg4.x + sk4.x;
    res.y = aggy * inv + bg4.y + sk4.y;
    res.z = aggz * inv + bg4.z + sk4.z;
    res.w = aggw * inv + bg4.w + sk4.w;
    if (do_relu) {
        res.x = fmaxf(res.x, 0.f); res.y = fmaxf(res.y, 0.f);
        res.z = fmaxf(res.z, 0.f); res.w = fmaxf(res.w, 0.f);
    }
    if (do_out) {
        float4 w01 = *(const float4*)&Wout[8 * sub];
        float4 w23 = *(const float4*)&Wout[8 * sub + 4];
        float o0 = res.x * w01.x + res.y * w01.z + res.z * w23.x + res.w * w23.z;
        float o1 = res.x * w01.y + res.y * w01.w + res.z * w23.y + res.w * w23.w;
        o0 = group_sum16(o0);
        o1 = group_sum16(o1);
        if (lane == 0) {
            outp[(size_t)i * 2 + 0] = o0 + bout[0];
            outp[(size_t)i * 2 + 1] = o1 + bout[1];
        }
    } else {
        if (grp == 0) {
            ushort4 h, l;
            h.x = bf16_rne(res.x); l.x = bf16_rne(res.x - bf16_to_f32(h.x));
            h.y = bf16_rne(res.y); l.y = bf16_rne(res.y - bf16_to_f32(h.y));
            h.z = bf16_rne(res.z); l.z = bf16_rne(res.z - bf16_to_f32(h.z));
            h.w = bf16_rne(res.w); l.w = bf16_rne(res.w - bf16_to_f32(h.w));
            *(ushort4*)&houtHi[(size_t)i * 64 + sub * 4] = h;
            *(ushort4*)&houtLo[(size_t)i * 64 + sub * 4] = l;
        }
    }
}

// ---------------- launch ----------------

extern "C" void kernel_launch(void* const* d_in, const int* in_sizes, int n_in,
                              void* d_out, int out_size, void* d_ws, size_t ws_size,
                              hipStream_t stream) {
    const float* x    = (const float*)d_in[0];
    const int*   ei   = (const int*)d_in[1];
    const float* Wl   = (const float*)d_in[2];
    const float* bl   = (const float*)d_in[3];
    const float* Wr   = (const float*)d_in[4];
    const float* br   = (const float*)d_in[5];
    const float* att  = (const float*)d_in[6];
    const float* bg   = (const float*)d_in[7];
    const float* Ws   = (const float*)d_in[8];
    const float* bs   = (const float*)d_in[9];
    const float* Wout = (const float*)d_in[10];
    const float* bout = (const float*)d_in[11];
    float* out = (float*)d_out;

    size_t off = 0;
    char* base = (char*)d_ws;
    auto alloc = [&](size_t bytes) -> void* {
        void* p = base + off;
        off += (bytes + 255) & ~(size_t)255;
        return p;
    };
    unsigned short* Xlb = (unsigned short*)alloc((size_t)NN * 64 * 2);
    float* XRS  = (float*)alloc((size_t)NN * 128 * 4);
    unsigned short* Ahi = (unsigned short*)alloc((size_t)NN * 64 * 2);
    unsigned short* Alo = (unsigned short*)alloc((size_t)NN * 64 * 2);
    unsigned short* Bhi = (unsigned short*)alloc((size_t)NN * 64 * 2);
    unsigned short* Blo = (unsigned short*)alloc((size_t)NN * 64 * 2);
    unsigned short* Wthi = (unsigned short*)alloc((size_t)9 * 4096 * 2);
    unsigned short* Wtlo = (unsigned short*)alloc((size_t)9 * 4096 * 2);
    int*  bhist  = (int*)alloc((size_t)NBUCK * 4);
    int*  bbase  = (int*)alloc((size_t)(NBUCK + 1) * 4);
    int*  bcur   = (int*)alloc((size_t)NBUCK * 4);
    unsigned int* bedges = (unsigned int*)alloc((size_t)EE * 4);
    int*  offs   = (int*)alloc((size_t)(NN + 1) * 4);
    int*  csr    = (int*)alloc((size_t)EE * 4);

    const int* src = ei;
    const int* dst = ei + EE;

    hipMemsetAsync(bhist, 0, (size_t)NBUCK * 4, stream);
    bucket_hist<<<SCWG, 256, 0, stream>>>(dst, bhist);
    bucket_scan<<<1, 512, 0, stream>>>(bhist, bbase, bcur, offs);
    bucket_scatter<<<SCWG, 256, 0, stream>>>(src, dst, bcur, bedges);
    bucket_csr<<<NBUCK, 256, 0, stream>>>(bedges, bbase, offs, csr);

    conv_w<<<(9 * 4096 + 255) / 256, 256, 0, stream>>>(Wl, Wr, Ws, Wthi, Wtlo);
    conv_x<<<2048, 256, 0, stream>>>(x, Ahi, Alo);

    unsigned short* curHi = Ahi; unsigned short* curLo = Alo;
    unsigned short* nxtHi = Bhi; unsigned short* nxtLo = Blo;
    for (int L = 0; L < 3; L++) {
        gemm_mfma<<<(NN + 63) / 64, 256, 0, stream>>>(
            curHi, curLo, Wthi + (size_t)L * 3 * 4096, Wtlo + (size_t)L * 3 * 4096,
            bl + L * 64, br + L * 64, bs + L * 64, Xlb, XRS);
        node_kernel<<<NN / 4, 256, 0, stream>>>(
            Xlb, XRS, offs, csr, att + L * 64, bg + L * 64,
            nxtHi, nxtLo, (L < 2) ? 1 : 0,
            Wout, bout, out, (L == 2) ? 1 : 0);
        unsigned short* th = curHi; curHi = nxtHi; nxtHi = th;
        unsigned short* tl = curLo; curLo = nxtLo; nxtLo = tl;
    }
}